// Round 1
// baseline (547.125 us; speedup 1.0000x reference)
//
#include <hip/hip_runtime.h>
#include <hip/hip_bf16.h>

#define Bn 2
#define Sn 4096
#define Dn 512
#define Hn 8
#define DKn 64

typedef __attribute__((ext_vector_type(8))) short bf16x8;
typedef __attribute__((ext_vector_type(4))) float f32x4;
typedef __attribute__((ext_vector_type(8))) unsigned short us8;
typedef __attribute__((ext_vector_type(4))) unsigned short us4;

__device__ __forceinline__ unsigned short f2bf(float f) {
  unsigned u = __builtin_bit_cast(unsigned, f);
  u += 0x7fffu + ((u >> 16) & 1u);   // RNE; inputs finite, no NaN path needed
  return (unsigned short)(u >> 16);
}

// ---------------------------------------------------------------- pack mask
// 32:1 compress int32 mask -> bitmask (4.2 MB, L2/LLC resident).
__global__ __launch_bounds__(256) void pack_mask_k(const int* __restrict__ mask,
                                                   unsigned int* __restrict__ pm) {
  int gid = blockIdx.x * 256 + threadIdx.x;
  int m = mask[gid];
  unsigned long long bal = __ballot(m != 0);
  if ((threadIdx.x & 63) == 0) {
    *(unsigned long long*)&pm[gid >> 5] = bal;  // gid multiple of 64 here
  }
}

// ---------------------------------------------------- weights -> bf16, W^T
// Wt[z][n][k] = W_z[k][n], z in {q,k,v,o}
__global__ __launch_bounds__(256) void wt_k(const float* __restrict__ wq,
                                            const float* __restrict__ wk,
                                            const float* __restrict__ wv,
                                            const float* __restrict__ wo,
                                            unsigned short* __restrict__ wt) {
  __shared__ unsigned short ls[64][68];  // 136B pitch -> 8B-aligned us4 rows
  const float* W = blockIdx.z == 0 ? wq : blockIdx.z == 1 ? wk
                 : blockIdx.z == 2 ? wv : wo;
  int k0 = blockIdx.x * 64, n0 = blockIdx.y * 64;
  int t = threadIdx.x;
  for (int j = 0; j < 4; ++j) {
    int i = t + j * 256;               // 1024 float4 chunks = 64x64 floats
    int r = i >> 4, c4 = (i & 15) << 2;
    float4 f = *(const float4*)&W[(size_t)(k0 + r) * 512 + n0 + c4];
    ls[c4 + 0][r] = f2bf(f.x);
    ls[c4 + 1][r] = f2bf(f.y);
    ls[c4 + 2][r] = f2bf(f.z);
    ls[c4 + 3][r] = f2bf(f.w);
  }
  __syncthreads();
  unsigned short* out = wt + (size_t)blockIdx.z * 512 * 512;
  for (int j = 0; j < 4; ++j) {
    int i = t + j * 256;
    int r = i >> 4, c4 = (i & 15) << 2;
    us4 v = {ls[r][c4], ls[r][c4 + 1], ls[r][c4 + 2], ls[r][c4 + 3]};
    *(us4*)&out[(size_t)(n0 + r) * 512 + k0 + c4] = v;
  }
}

// ------------------------------------------------------------------- GEMM
// C[8192,512] = A[8192,512] @ W[512,512], BM=128 BN=64 BK=64, 4 waves.
// HEADS: out bf16 scattered to [b,h,s,dk] (z selects q/k/v; Q scaled 1/8).
// else: out fp32 linear.
template <bool A_F32, bool HEADS>
__global__ __launch_bounds__(256, 2) void gemm_k(
    const float* __restrict__ a0, const float* __restrict__ a1,
    const float* __restrict__ a2, const unsigned short* __restrict__ abf,
    const unsigned short* __restrict__ wt, unsigned short* __restrict__ oh,
    float* __restrict__ olin) {
  __shared__ unsigned short As[128 * 72];  // pitch 72 bf16 = 144 B (16B-aligned, +8 pad)
  __shared__ unsigned short Bs[64 * 72];
  const int z = blockIdx.z;
  const unsigned short* Wt = wt + (size_t)z * 512 * 512;
  const float scale = (HEADS && z == 0) ? 0.125f : 1.0f;
  const int m0 = blockIdx.x * 128, n0 = blockIdx.y * 64;
  const int t = threadIdx.x, w = t >> 6, l = t & 63;

  f32x4 acc[2][4] = {};

  for (int k0 = 0; k0 < 512; k0 += 64) {
    __syncthreads();
    if constexpr (A_F32) {
      const float* A32 = z == 0 ? a0 : (z == 1 ? a1 : a2);
      for (int j = 0; j < 8; ++j) {
        int i = t + j * 256;            // 2048 float4 chunks = 128x64 floats
        int r = i >> 4, c4 = (i & 15) << 2;
        float4 f = *(const float4*)&A32[(size_t)(m0 + r) * 512 + k0 + c4];
        us4 v = {f2bf(f.x), f2bf(f.y), f2bf(f.z), f2bf(f.w)};
        *(us4*)&As[r * 72 + c4] = v;
      }
    } else {
      for (int j = 0; j < 4; ++j) {
        int i = t + j * 256;            // 1024 us8 chunks
        int r = i >> 3, c8 = (i & 7) << 3;
        *(us8*)&As[r * 72 + c8] =
            *(const us8*)&abf[(size_t)(m0 + r) * 512 + k0 + c8];
      }
    }
    for (int j = 0; j < 2; ++j) {
      int i = t + j * 256;              // 512 us8 chunks = 64x64 bf16
      int r = i >> 3, c8 = (i & 7) << 3;
      *(us8*)&Bs[r * 72 + c8] =
          *(const us8*)&Wt[(size_t)(n0 + r) * 512 + k0 + c8];
    }
    __syncthreads();

#pragma unroll
    for (int ks = 0; ks < 2; ++ks) {
      bf16x8 aA[2], bB[4];
#pragma unroll
      for (int mt = 0; mt < 2; ++mt)
        aA[mt] = *(const bf16x8*)&As[(w * 32 + mt * 16 + (l & 15)) * 72 +
                                     ((l >> 4) << 3) + ks * 32];
#pragma unroll
      for (int nt = 0; nt < 4; ++nt)
        bB[nt] = *(const bf16x8*)&Bs[(nt * 16 + (l & 15)) * 72 +
                                     ((l >> 4) << 3) + ks * 32];
#pragma unroll
      for (int mt = 0; mt < 2; ++mt)
#pragma unroll
        for (int nt = 0; nt < 4; ++nt)
          acc[mt][nt] = __builtin_amdgcn_mfma_f32_16x16x32_bf16(
              aA[mt], bB[nt], acc[mt][nt], 0, 0, 0);
    }
  }

#pragma unroll
  for (int mt = 0; mt < 2; ++mt)
#pragma unroll
    for (int nt = 0; nt < 4; ++nt)
#pragma unroll
      for (int r = 0; r < 4; ++r) {
        int m = m0 + w * 32 + mt * 16 + ((l >> 4) << 2) + r;
        int n = n0 + nt * 16 + (l & 15);
        float val = acc[mt][nt][r] * scale;
        if constexpr (HEADS) {
          int b = m >> 12, s = m & 4095, h = n >> 6, dk = n & 63;
          oh[(size_t)z * (Bn * Hn * Sn * DKn) +
             ((size_t)(b * Hn + h) * Sn + s) * DKn + dk] = f2bf(val);
        } else {
          olin[(size_t)m * 512 + n] = val;
        }
      }
}

// ------------------------------------------------------------- flash attn
// One block per (b, h, 128-row Q tile). KV tiles of 64. 4 waves x 32 q-rows.
__global__ __launch_bounds__(256, 2) void flash_k(
    const unsigned short* __restrict__ Qh, const unsigned short* __restrict__ Kh,
    const unsigned short* __restrict__ Vh, const unsigned int* __restrict__ pm,
    unsigned short* __restrict__ attn) {
  __shared__ unsigned short Qs[128 * 72];
  __shared__ unsigned short Ks[64 * 72];
  __shared__ unsigned short Vts[64 * 72];   // Vt[dk][kv], kv XOR-swizzled
  __shared__ unsigned short Ps[4 * 32 * 72];
  __shared__ unsigned int Mw[256];          // [128 rows][2 words]

  const int q0 = blockIdx.x * 128, h = blockIdx.y, b = blockIdx.z;
  const int t = threadIdx.x, w = t >> 6, l = t & 63;
  const size_t hb = (size_t)(b * Hn + h) * Sn * DKn;
  const unsigned short* Qg = Qh + hb;
  const unsigned short* Kg = Kh + hb;
  const unsigned short* Vg = Vh + hb;

  for (int j = 0; j < 4; ++j) {             // stage Q once: 1024 us8 chunks
    int i = t + j * 256;
    int r = i >> 3, c8 = (i & 7) << 3;
    *(us8*)&Qs[r * 72 + c8] = *(const us8*)&Qg[(size_t)(q0 + r) * 64 + c8];
  }

  f32x4 oacc[2][4] = {};
  float mrow[2][4], lrow[2][4];
#pragma unroll
  for (int mt = 0; mt < 2; ++mt)
#pragma unroll
    for (int r = 0; r < 4; ++r) { mrow[mt][r] = -__builtin_inff(); lrow[mt][r] = 0.f; }

  unsigned short* Pw = Ps + w * 32 * 72;

  for (int kv0 = 0; kv0 < Sn; kv0 += 64) {
    __syncthreads();
    for (int j = 0; j < 2; ++j) {           // stage K: 512 us8 chunks
      int i = t + j * 256;
      int r = i >> 3, c8 = (i & 7) << 3;
      *(us8*)&Ks[r * 72 + c8] = *(const us8*)&Kg[(size_t)(kv0 + r) * 64 + c8];
    }
    for (int j = 0; j < 2; ++j) {           // stage V transposed+swizzled
      int i = t + j * 256;
      int r = i >> 3, c8 = (i & 7) << 3;    // kv row r, dk base c8
      us8 vv = *(const us8*)&Vg[(size_t)(kv0 + r) * 64 + c8];
#pragma unroll
      for (int x = 0; x < 8; ++x) {
        int dk = c8 + x;
        Vts[dk * 72 + (r ^ (dk & 56))] = ((const unsigned short*)&vv)[x];
      }
    }
    {                                       // stage mask words
      int r = t >> 1, ww = t & 1;
      Mw[t] = pm[((size_t)b * Sn + q0 + r) * (Sn / 32) + (kv0 >> 5) + ww];
    }
    __syncthreads();

    // ---- S = Q K^T
    f32x4 sacc[2][4] = {};
#pragma unroll
    for (int ks = 0; ks < 2; ++ks) {
      bf16x8 aQ[2], bK[4];
#pragma unroll
      for (int mt = 0; mt < 2; ++mt)
        aQ[mt] = *(const bf16x8*)&Qs[(w * 32 + mt * 16 + (l & 15)) * 72 +
                                     ((l >> 4) << 3) + ks * 32];
#pragma unroll
      for (int nt = 0; nt < 4; ++nt)
        bK[nt] = *(const bf16x8*)&Ks[(nt * 16 + (l & 15)) * 72 +
                                     ((l >> 4) << 3) + ks * 32];
#pragma unroll
      for (int mt = 0; mt < 2; ++mt)
#pragma unroll
        for (int nt = 0; nt < 4; ++nt)
          sacc[mt][nt] = __builtin_amdgcn_mfma_f32_16x16x32_bf16(
              aQ[mt], bK[nt], sacc[mt][nt], 0, 0, 0);
    }

    // ---- mask + online softmax (C layout: col=l&15, row=(l>>4)*4+reg)
#pragma unroll
    for (int mt = 0; mt < 2; ++mt) {
#pragma unroll
      for (int r = 0; r < 4; ++r) {
        int qloc = w * 32 + mt * 16 + ((l >> 4) << 2) + r;
        unsigned mw0 = Mw[qloc * 2 + 0];
        unsigned mw1 = Mw[qloc * 2 + 1];
        int c = l & 15;
        float v0 = ((mw0 >> c) & 1u)        ? sacc[mt][0][r] : -1e9f;
        float v1 = ((mw0 >> (c + 16)) & 1u) ? sacc[mt][1][r] : -1e9f;
        float v2 = ((mw1 >> c) & 1u)        ? sacc[mt][2][r] : -1e9f;
        float v3 = ((mw1 >> (c + 16)) & 1u) ? sacc[mt][3][r] : -1e9f;
        float mx = fmaxf(fmaxf(v0, v1), fmaxf(v2, v3));
#pragma unroll
        for (int d = 1; d < 16; d <<= 1) mx = fmaxf(mx, __shfl_xor(mx, d, 64));
        float mnew = fmaxf(mrow[mt][r], mx);
        const float L2E = 1.44269504088896f;
        float alpha = __builtin_amdgcn_exp2f((mrow[mt][r] - mnew) * L2E);
        float p0 = __builtin_amdgcn_exp2f((v0 - mnew) * L2E);
        float p1 = __builtin_amdgcn_exp2f((v1 - mnew) * L2E);
        float p2 = __builtin_amdgcn_exp2f((v2 - mnew) * L2E);
        float p3 = __builtin_amdgcn_exp2f((v3 - mnew) * L2E);
        float ps = (p0 + p1) + (p2 + p3);
#pragma unroll
        for (int d = 1; d < 16; d <<= 1) ps += __shfl_xor(ps, d, 64);
        lrow[mt][r] = lrow[mt][r] * alpha + ps;
        mrow[mt][r] = mnew;
#pragma unroll
        for (int dt = 0; dt < 4; ++dt) oacc[mt][dt][r] *= alpha;
        int prow = mt * 16 + ((l >> 4) << 2) + r;   // P -> A-layout via LDS
        Pw[prow * 72 + c]      = f2bf(p0);
        Pw[prow * 72 + 16 + c] = f2bf(p1);
        Pw[prow * 72 + 32 + c] = f2bf(p2);
        Pw[prow * 72 + 48 + c] = f2bf(p3);
      }
    }

    // ---- O += P @ V
#pragma unroll
    for (int ks = 0; ks < 2; ++ks) {
      bf16x8 aP[2], bV[4];
#pragma unroll
      for (int mt = 0; mt < 2; ++mt)
        aP[mt] = *(const bf16x8*)&Pw[(mt * 16 + (l & 15)) * 72 +
                                     ((l >> 4) << 3) + ks * 32];
#pragma unroll
      for (int dt = 0; dt < 4; ++dt) {
        int dk = dt * 16 + (l & 15);
        int kb = ((l >> 4) << 3) + ks * 32;
        bV[dt] = *(const bf16x8*)&Vts[dk * 72 + (kb ^ (dk & 56))];
      }
#pragma unroll
      for (int mt = 0; mt < 2; ++mt)
#pragma unroll
        for (int dt = 0; dt < 4; ++dt)
          oacc[mt][dt] = __builtin_amdgcn_mfma_f32_16x16x32_bf16(
              aP[mt], bV[dt], oacc[mt][dt], 0, 0, 0);
    }
  }

  // epilogue: merged-head layout [b][s][h*64+dk]
#pragma unroll
  for (int mt = 0; mt < 2; ++mt)
#pragma unroll
    for (int r = 0; r < 4; ++r) {
      float inv = 1.0f / lrow[mt][r];
      int qrow = q0 + w * 32 + mt * 16 + ((l >> 4) << 2) + r;
#pragma unroll
      for (int dt = 0; dt < 4; ++dt) {
        int dk = dt * 16 + (l & 15);
        attn[((size_t)(b * Sn + qrow)) * Dn + h * DKn + dk] =
            f2bf(oacc[mt][dt][r] * inv);
      }
    }
}

// ------------------------------------------------------------------ launch
extern "C" void kernel_launch(void* const* d_in, const int* in_sizes, int n_in,
                              void* d_out, int out_size, void* d_ws,
                              size_t ws_size, hipStream_t stream) {
  const float* q = (const float*)d_in[0];
  const float* k = (const float*)d_in[1];
  const float* v = (const float*)d_in[2];
  const int* mask = (const int*)d_in[3];
  const float* wq = (const float*)d_in[4];
  const float* wk = (const float*)d_in[5];
  const float* wv = (const float*)d_in[6];
  const float* wo = (const float*)d_in[7];
  float* out = (float*)d_out;

  char* ws = (char*)d_ws;
  const size_t headN = (size_t)Bn * Hn * Sn * DKn;  // 4194304 elems per tensor
  unsigned short* qkv = (unsigned short*)ws;
  size_t off = 3 * headN * 2;
  unsigned short* attn = (unsigned short*)(ws + off);
  off += (size_t)Bn * Sn * Dn * 2;
  unsigned short* wt = (unsigned short*)(ws + off);
  off += 4ull * 512 * 512 * 2;
  unsigned int* pm = (unsigned int*)(ws + off);

  pack_mask_k<<<(Bn * Sn * Sn) / 256, 256, 0, stream>>>(mask, pm);
  wt_k<<<dim3(8, 8, 4), 256, 0, stream>>>(wq, wk, wv, wo, wt);
  gemm_k<true, true><<<dim3(64, 8, 3), 256, 0, stream>>>(
      q, k, v, nullptr, wt, qkv, nullptr);
  flash_k<<<dim3(32, 8, 2), 256, 0, stream>>>(qkv, qkv + headN,
                                              qkv + 2 * headN, pm, attn);
  gemm_k<false, false><<<dim3(64, 8, 1), 256, 0, stream>>>(
      nullptr, nullptr, nullptr, attn, wt + 3ull * 512 * 512, nullptr, out);
}

// Round 2
// 477.421 us; speedup vs baseline: 1.1460x; 1.1460x over previous
//
#include <hip/hip_runtime.h>
#include <hip/hip_bf16.h>

#define Bn 2
#define Sn 4096
#define Dn 512
#define Hn 8
#define DKn 64

typedef __attribute__((ext_vector_type(8))) short bf16x8;
typedef __attribute__((ext_vector_type(4))) float f32x4;
typedef __attribute__((ext_vector_type(8))) unsigned short us8;
typedef __attribute__((ext_vector_type(4))) unsigned short us4;

__device__ __forceinline__ unsigned short f2bf(float f) {
  unsigned u = __builtin_bit_cast(unsigned, f);
  u += 0x7fffu + ((u >> 16) & 1u);   // RNE; inputs finite
  return (unsigned short)(u >> 16);
}

// ---------------------------------------------------------------- pack mask
__global__ __launch_bounds__(256) void pack_mask_k(const int* __restrict__ mask,
                                                   unsigned int* __restrict__ pm) {
  int gid = blockIdx.x * 256 + threadIdx.x;
  int m = mask[gid];
  unsigned long long bal = __ballot(m != 0);
  if ((threadIdx.x & 63) == 0) {
    *(unsigned long long*)&pm[gid >> 5] = bal;
  }
}

// ------------------------------------------------------- fp32 -> bf16 copy
__global__ __launch_bounds__(256) void cvt_k(const float* __restrict__ q,
                                             const float* __restrict__ k,
                                             const float* __restrict__ v,
                                             unsigned short* __restrict__ o) {
  const float* src = blockIdx.y == 0 ? q : blockIdx.y == 1 ? k : v;
  size_t i = (size_t)blockIdx.x * 256 + threadIdx.x;
  float4 f = *(const float4*)&src[i * 4];
  us4 r = {f2bf(f.x), f2bf(f.y), f2bf(f.z), f2bf(f.w)};
  *(us4*)&o[(size_t)blockIdx.y * (Bn * Sn * Dn) + i * 4] = r;
}

// ---------------------------------------------------- weights -> bf16, W^T
__global__ __launch_bounds__(256) void wt_k(const float* __restrict__ wq,
                                            const float* __restrict__ wk,
                                            const float* __restrict__ wv,
                                            const float* __restrict__ wo,
                                            unsigned short* __restrict__ wt) {
  __shared__ unsigned short ls[64][68];
  const float* W = blockIdx.z == 0 ? wq : blockIdx.z == 1 ? wk
                 : blockIdx.z == 2 ? wv : wo;
  int k0 = blockIdx.x * 64, n0 = blockIdx.y * 64;
  int t = threadIdx.x;
  for (int j = 0; j < 4; ++j) {
    int i = t + j * 256;
    int r = i >> 4, c4 = (i & 15) << 2;
    float4 f = *(const float4*)&W[(size_t)(k0 + r) * 512 + n0 + c4];
    ls[c4 + 0][r] = f2bf(f.x);
    ls[c4 + 1][r] = f2bf(f.y);
    ls[c4 + 2][r] = f2bf(f.z);
    ls[c4 + 3][r] = f2bf(f.w);
  }
  __syncthreads();
  unsigned short* out = wt + (size_t)blockIdx.z * 512 * 512;
  for (int j = 0; j < 4; ++j) {
    int i = t + j * 256;
    int r = i >> 4, c4 = (i & 15) << 2;
    us4 v = {ls[r][c4], ls[r][c4 + 1], ls[r][c4 + 2], ls[r][c4 + 3]};
    *(us4*)&out[(size_t)(n0 + r) * 512 + k0 + c4] = v;
  }
}

// ------------------------------------------------- V-heads transpose kernel
// Vh [bh][s][dk] -> Vt [bh][dk][s]
__global__ __launch_bounds__(256) void vt_k(const unsigned short* __restrict__ Vh,
                                            unsigned short* __restrict__ Vt) {
  __shared__ unsigned short ls[64][72];
  int bh = blockIdx.y, s0 = blockIdx.x * 64;
  const unsigned short* src = Vh + (size_t)bh * Sn * DKn;
  unsigned short* dst = Vt + (size_t)bh * Sn * DKn;
  int t = threadIdx.x;
  for (int j = 0; j < 2; ++j) {
    int i = t + j * 256;
    int r = i >> 3, c8 = (i & 7) << 3;
    us8 v = *(const us8*)&src[(size_t)(s0 + r) * 64 + c8];
#pragma unroll
    for (int x = 0; x < 8; ++x) ls[c8 + x][r] = ((unsigned short*)&v)[x];
  }
  __syncthreads();
  for (int j = 0; j < 2; ++j) {
    int i = t + j * 256;
    int r = i >> 3, c8 = (i & 7) << 3;   // r = dk, c8 = s_local
    us8 v;
#pragma unroll
    for (int x = 0; x < 8; ++x) ((unsigned short*)&v)[x] = ls[r][c8 + x];
    *(us8*)&dst[(size_t)r * Sn + s0 + c8] = v;
  }
}

// ------------------------------------------------------------------- GEMM
// C[8192,512] = A_bf16[8192,512] @ W[512,512], BM=128 BN=64 BK=64, 4 waves.
template <bool HEADS>
__global__ __launch_bounds__(256, 2) void gemm_k(
    const unsigned short* __restrict__ A0, size_t zstride,
    const unsigned short* __restrict__ wt, unsigned short* __restrict__ oh,
    float* __restrict__ olin) {
  __shared__ unsigned short As[128 * 72];
  __shared__ unsigned short Bs[64 * 72];
  const int z = blockIdx.z;
  const unsigned short* A = A0 + zstride * z;
  const unsigned short* Wt = wt + (size_t)z * 512 * 512;
  const float scale = (HEADS && z == 0) ? 0.125f * 1.44269504088896f : 1.0f;
  const int m0 = blockIdx.x * 128, n0 = blockIdx.y * 64;
  const int t = threadIdx.x, w = t >> 6, l = t & 63;

  f32x4 acc[2][4] = {};

  for (int k0 = 0; k0 < 512; k0 += 64) {
    __syncthreads();
    for (int j = 0; j < 4; ++j) {
      int i = t + j * 256;
      int r = i >> 3, c8 = (i & 7) << 3;
      *(us8*)&As[r * 72 + c8] = *(const us8*)&A[(size_t)(m0 + r) * 512 + k0 + c8];
    }
    for (int j = 0; j < 2; ++j) {
      int i = t + j * 256;
      int r = i >> 3, c8 = (i & 7) << 3;
      *(us8*)&Bs[r * 72 + c8] = *(const us8*)&Wt[(size_t)(n0 + r) * 512 + k0 + c8];
    }
    __syncthreads();

#pragma unroll
    for (int ks = 0; ks < 2; ++ks) {
      bf16x8 aA[2], bB[4];
#pragma unroll
      for (int mt = 0; mt < 2; ++mt)
        aA[mt] = *(const bf16x8*)&As[(w * 32 + mt * 16 + (l & 15)) * 72 +
                                     ((l >> 4) << 3) + ks * 32];
#pragma unroll
      for (int nt = 0; nt < 4; ++nt)
        bB[nt] = *(const bf16x8*)&Bs[(nt * 16 + (l & 15)) * 72 +
                                     ((l >> 4) << 3) + ks * 32];
#pragma unroll
      for (int mt = 0; mt < 2; ++mt)
#pragma unroll
        for (int nt = 0; nt < 4; ++nt)
          acc[mt][nt] = __builtin_amdgcn_mfma_f32_16x16x32_bf16(
              aA[mt], bB[nt], acc[mt][nt], 0, 0, 0);
    }
  }

#pragma unroll
  for (int mt = 0; mt < 2; ++mt)
#pragma unroll
    for (int nt = 0; nt < 4; ++nt)
#pragma unroll
      for (int r = 0; r < 4; ++r) {
        int m = m0 + w * 32 + mt * 16 + ((l >> 4) << 2) + r;
        int n = n0 + nt * 16 + (l & 15);
        float val = acc[mt][nt][r] * scale;
        if constexpr (HEADS) {
          int b = m >> 12, s = m & 4095, h = n >> 6, dk = n & 63;
          oh[(size_t)z * (Bn * Hn * Sn * DKn) +
             ((size_t)(b * Hn + h) * Sn + s) * DKn + dk] = f2bf(val);
        } else {
          olin[(size_t)m * 512 + n] = val;
        }
      }
}

// ------------------------------------------------------------- flash attn
// Static-max online-free softmax: Q pre-scaled by log2(e)/8, p = exp2(s).
// XOR-swizzled pitch-64 LDS; V consumed pre-transposed [dk][s].
__global__ __launch_bounds__(256, 3) void flash_k(
    const unsigned short* __restrict__ Qh, const unsigned short* __restrict__ Kh,
    const unsigned short* __restrict__ VtG, const unsigned int* __restrict__ pm,
    unsigned short* __restrict__ attn) {
  __shared__ unsigned short Qs[128 * 64];
  __shared__ unsigned short Ks[64 * 64];
  __shared__ unsigned short Vts[64 * 64];
  __shared__ unsigned short Ps[4 * 32 * 64];
  __shared__ unsigned int Mw[256];

  const int q0 = blockIdx.x * 128, h = blockIdx.y, b = blockIdx.z;
  const int t = threadIdx.x, w = t >> 6, l = t & 63;
  const size_t hb = (size_t)(b * Hn + h) * Sn * DKn;
  const unsigned short* Qg = Qh + hb;
  const unsigned short* Kg = Kh + hb;
  const unsigned short* Vg = VtG + hb;   // [dk][s]

  for (int j = 0; j < 4; ++j) {          // stage Q once (swizzled)
    int i = t + j * 256;
    int r = i >> 3, cc = i & 7;
    *(us8*)&Qs[r * 64 + ((cc ^ (r & 7)) << 3)] =
        *(const us8*)&Qg[(size_t)(q0 + r) * 64 + (cc << 3)];
  }

  f32x4 oacc[2][4] = {};
  float lsum[2][4] = {};
  const int qquad = (l >> 4) << 2;
  const int c = l & 15;
  unsigned short* Pw = Ps + w * (32 * 64);

  for (int kv0 = 0; kv0 < Sn; kv0 += 64) {
    __syncthreads();
    for (int j = 0; j < 2; ++j) {
      int i = t + j * 256;
      int r = i >> 3, cc = i & 7;
      *(us8*)&Ks[r * 64 + ((cc ^ (r & 7)) << 3)] =
          *(const us8*)&Kg[(size_t)(kv0 + r) * 64 + (cc << 3)];
      *(us8*)&Vts[r * 64 + ((cc ^ (r & 7)) << 3)] =
          *(const us8*)&Vg[(size_t)r * Sn + kv0 + (cc << 3)];
    }
    Mw[t] = pm[((size_t)b * Sn + q0 + (t >> 1)) * (Sn / 32) + (kv0 >> 5) + (t & 1)];
    __syncthreads();

    // ---- S = Q K^T (log2 units)
    f32x4 sacc[2][4] = {};
#pragma unroll
    for (int ks = 0; ks < 2; ++ks) {
      bf16x8 aQ[2], bK[4];
      int ch = (l >> 4) + ks * 4;
#pragma unroll
      for (int mt = 0; mt < 2; ++mt) {
        int row = w * 32 + mt * 16 + c;
        aQ[mt] = *(const bf16x8*)&Qs[row * 64 + ((ch ^ (row & 7)) << 3)];
      }
#pragma unroll
      for (int nt = 0; nt < 4; ++nt) {
        int row = nt * 16 + c;
        bK[nt] = *(const bf16x8*)&Ks[row * 64 + ((ch ^ (row & 7)) << 3)];
      }
#pragma unroll
      for (int mt = 0; mt < 2; ++mt)
#pragma unroll
        for (int nt = 0; nt < 4; ++nt)
          sacc[mt][nt] = __builtin_amdgcn_mfma_f32_16x16x32_bf16(
              aQ[mt], bK[nt], sacc[mt][nt], 0, 0, 0);
    }

    // ---- masked exp2, accumulate row-sum partials, P -> LDS (A-layout)
#pragma unroll
    for (int mt = 0; mt < 2; ++mt) {
      unsigned mw[8];
      int qb2 = (w * 32 + mt * 16 + qquad) * 2;
      *(uint4*)&mw[0] = *(const uint4*)&Mw[qb2];
      *(uint4*)&mw[4] = *(const uint4*)&Mw[qb2 + 4];
#pragma unroll
      for (int r = 0; r < 4; ++r) {
        unsigned m0 = mw[r * 2], m1 = mw[r * 2 + 1];
        float p0 = ((m0 >> c) & 1u)        ? __builtin_amdgcn_exp2f(sacc[mt][0][r]) : 0.f;
        float p1 = ((m0 >> (c + 16)) & 1u) ? __builtin_amdgcn_exp2f(sacc[mt][1][r]) : 0.f;
        float p2 = ((m1 >> c) & 1u)        ? __builtin_amdgcn_exp2f(sacc[mt][2][r]) : 0.f;
        float p3 = ((m1 >> (c + 16)) & 1u) ? __builtin_amdgcn_exp2f(sacc[mt][3][r]) : 0.f;
        lsum[mt][r] += (p0 + p1) + (p2 + p3);
        int prow = mt * 16 + qquad + r;
        int sw = prow & 7;
        unsigned short* Pr = Pw + prow * 64 + (c & 7);
        Pr[(((c >> 3) | 0) ^ sw) << 3] = f2bf(p0);
        Pr[(((c >> 3) | 2) ^ sw) << 3] = f2bf(p1);
        Pr[(((c >> 3) | 4) ^ sw) << 3] = f2bf(p2);
        Pr[(((c >> 3) | 6) ^ sw) << 3] = f2bf(p3);
      }
    }

    // ---- O += P @ V
#pragma unroll
    for (int ks = 0; ks < 2; ++ks) {
      bf16x8 aP[2], bV[4];
      int ch = (l >> 4) + ks * 4;
#pragma unroll
      for (int mt = 0; mt < 2; ++mt) {
        int row = mt * 16 + c;
        aP[mt] = *(const bf16x8*)&Pw[row * 64 + ((ch ^ (row & 7)) << 3)];
      }
#pragma unroll
      for (int dt = 0; dt < 4; ++dt) {
        int row = dt * 16 + c;
        bV[dt] = *(const bf16x8*)&Vts[row * 64 + ((ch ^ (row & 7)) << 3)];
      }
#pragma unroll
      for (int mt = 0; mt < 2; ++mt)
#pragma unroll
        for (int dt = 0; dt < 4; ++dt)
          oacc[mt][dt] = __builtin_amdgcn_mfma_f32_16x16x32_bf16(
              aP[mt], bV[dt], oacc[mt][dt], 0, 0, 0);
    }
  }

  // epilogue: one butterfly per row, normalize, merged-head store
#pragma unroll
  for (int mt = 0; mt < 2; ++mt)
#pragma unroll
    for (int r = 0; r < 4; ++r) {
      float s = lsum[mt][r];
#pragma unroll
      for (int d = 1; d < 16; d <<= 1) s += __shfl_xor(s, d, 64);
      float inv = 1.0f / s;
      int qrow = q0 + w * 32 + mt * 16 + qquad + r;
#pragma unroll
      for (int dt = 0; dt < 4; ++dt) {
        attn[((size_t)(b * Sn + qrow)) * Dn + h * DKn + dt * 16 + c] =
            f2bf(oacc[mt][dt][r] * inv);
      }
    }
}

// ------------------------------------------------------------------ launch
extern "C" void kernel_launch(void* const* d_in, const int* in_sizes, int n_in,
                              void* d_out, int out_size, void* d_ws,
                              size_t ws_size, hipStream_t stream) {
  const float* q = (const float*)d_in[0];
  const float* k = (const float*)d_in[1];
  const float* v = (const float*)d_in[2];
  const int* mask = (const int*)d_in[3];
  const float* wq = (const float*)d_in[4];
  const float* wk = (const float*)d_in[5];
  const float* wv = (const float*)d_in[6];
  const float* wo = (const float*)d_in[7];
  float* out = (float*)d_out;

  char* ws = (char*)d_ws;
  const size_t headN = (size_t)Bn * Hn * Sn * DKn;        // 4,194,304 elems
  const size_t tensB = headN * 2;                          // 8,388,608 bytes
  // region A: qb/kb/vb bf16 (3*tensB); after proj-gemm reused: vtg, attn
  unsigned short* qbkb = (unsigned short*)ws;
  unsigned short* vtg  = (unsigned short*)ws;              // reuse (post-gemm)
  unsigned short* attn = (unsigned short*)(ws + tensB);    // reuse (post-gemm)
  size_t off = 3 * tensB;
  unsigned short* qkv = (unsigned short*)(ws + off);       // 3*tensB
  off += 3 * tensB;
  unsigned short* wt = (unsigned short*)(ws + off);        // 2 MB
  off += 4ull * 512 * 512 * 2;
  unsigned int* pm = (unsigned int*)(ws + off);            // 4 MB

  pack_mask_k<<<(Bn * Sn * Sn) / 256, 256, 0, stream>>>(mask, pm);
  cvt_k<<<dim3(4096, 3), 256, 0, stream>>>(q, k, v, qbkb);
  wt_k<<<dim3(8, 8, 4), 256, 0, stream>>>(wq, wk, wv, wo, wt);
  gemm_k<true><<<dim3(64, 8, 3), 256, 0, stream>>>(qbkb, headN, wt, qkv, nullptr);
  vt_k<<<dim3(Sn / 64, Bn * Hn), 256, 0, stream>>>(qkv + 2 * headN, vtg);
  flash_k<<<dim3(32, 8, 2), 256, 0, stream>>>(qkv, qkv + headN, vtg, pm, attn);
  gemm_k<false><<<dim3(64, 8, 1), 256, 0, stream>>>(
      attn, 0, wt + 3ull * 512 * 512, nullptr, out);
}

// Round 3
// 438.474 us; speedup vs baseline: 1.2478x; 1.0888x over previous
//
#include <hip/hip_runtime.h>
#include <hip/hip_bf16.h>

#define Bn 2
#define Sn 4096
#define Dn 512
#define Hn 8
#define DKn 64

typedef __attribute__((ext_vector_type(8))) short bf16x8;
typedef __attribute__((ext_vector_type(4))) float f32x4;
typedef __attribute__((ext_vector_type(4))) _Float16 f16x4;
typedef __attribute__((ext_vector_type(8))) unsigned short us8;
typedef __attribute__((ext_vector_type(4))) unsigned short us4;

__device__ __forceinline__ unsigned short f2bf(float f) {
  unsigned u = __builtin_bit_cast(unsigned, f);
  u += 0x7fffu + ((u >> 16) & 1u);   // RNE; inputs finite
  return (unsigned short)(u >> 16);
}

// ---------------------------------------------------------------- pack mask
// 32:1 compress, output TRANSPOSED: pm[b][kvw][q] so flash staging coalesces.
__global__ __launch_bounds__(256) void pack_mask_k(const int* __restrict__ mask,
                                                   unsigned int* __restrict__ pm) {
  int gid = blockIdx.x * 256 + threadIdx.x;
  int m = mask[gid];
  unsigned long long bal = __ballot(m != 0);
  if ((threadIdx.x & 63) == 0) {
    int q = (gid >> 12) & 4095;
    int b = gid >> 24;
    int kvw = (gid >> 5) & 127;
    pm[((size_t)b * 128 + kvw) * 4096 + q] = (unsigned)bal;
    pm[((size_t)b * 128 + kvw + 1) * 4096 + q] = (unsigned)(bal >> 32);
  }
}

// ------------------------------------------------------- fp32 -> bf16 copy
__global__ __launch_bounds__(256) void cvt_k(const float* __restrict__ q,
                                             const float* __restrict__ k,
                                             const float* __restrict__ v,
                                             unsigned short* __restrict__ o) {
  const float* src = blockIdx.y == 0 ? q : blockIdx.y == 1 ? k : v;
  size_t i = (size_t)blockIdx.x * 256 + threadIdx.x;
  float4 f = *(const float4*)&src[i * 4];
  us4 r = {f2bf(f.x), f2bf(f.y), f2bf(f.z), f2bf(f.w)};
  *(us4*)&o[(size_t)blockIdx.y * (Bn * Sn * Dn) + i * 4] = r;
}

// ---------------------------------------------------- weights -> bf16, W^T
__global__ __launch_bounds__(256) void wt_k(const float* __restrict__ wq,
                                            const float* __restrict__ wk,
                                            const float* __restrict__ wv,
                                            const float* __restrict__ wo,
                                            unsigned short* __restrict__ wt) {
  __shared__ unsigned short ls[64][68];
  const float* W = blockIdx.z == 0 ? wq : blockIdx.z == 1 ? wk
                 : blockIdx.z == 2 ? wv : wo;
  int k0 = blockIdx.x * 64, n0 = blockIdx.y * 64;
  int t = threadIdx.x;
  for (int j = 0; j < 4; ++j) {
    int i = t + j * 256;
    int r = i >> 4, c4 = (i & 15) << 2;
    float4 f = *(const float4*)&W[(size_t)(k0 + r) * 512 + n0 + c4];
    ls[c4 + 0][r] = f2bf(f.x);
    ls[c4 + 1][r] = f2bf(f.y);
    ls[c4 + 2][r] = f2bf(f.z);
    ls[c4 + 3][r] = f2bf(f.w);
  }
  __syncthreads();
  unsigned short* out = wt + (size_t)blockIdx.z * 512 * 512;
  for (int j = 0; j < 4; ++j) {
    int i = t + j * 256;
    int r = i >> 4, c4 = (i & 15) << 2;
    us4 v = {ls[r][c4], ls[r][c4 + 1], ls[r][c4 + 2], ls[r][c4 + 3]};
    *(us4*)&out[(size_t)(n0 + r) * 512 + k0 + c4] = v;
  }
}

// ------------------------------------------------- V-heads transpose kernel
// Vh [bh][s][dk] -> Vt [bh][dk][s]  (dtype-agnostic 16-bit moves)
__global__ __launch_bounds__(256) void vt_k(const unsigned short* __restrict__ Vh,
                                            unsigned short* __restrict__ Vt) {
  __shared__ unsigned short ls[64][72];
  int bh = blockIdx.y, s0 = blockIdx.x * 64;
  const unsigned short* src = Vh + (size_t)bh * Sn * DKn;
  unsigned short* dst = Vt + (size_t)bh * Sn * DKn;
  int t = threadIdx.x;
  for (int j = 0; j < 2; ++j) {
    int i = t + j * 256;
    int r = i >> 3, c8 = (i & 7) << 3;
    us8 v = *(const us8*)&src[(size_t)(s0 + r) * 64 + c8];
#pragma unroll
    for (int x = 0; x < 8; ++x) ls[c8 + x][r] = ((unsigned short*)&v)[x];
  }
  __syncthreads();
  for (int j = 0; j < 2; ++j) {
    int i = t + j * 256;
    int r = i >> 3, c8 = (i & 7) << 3;
    us8 v;
#pragma unroll
    for (int x = 0; x < 8; ++x) ((unsigned short*)&v)[x] = ls[r][c8 + x];
    *(us8*)&dst[(size_t)r * Sn + s0 + c8] = v;
  }
}

// ------------------------------------------------------------------- GEMM
// C[8192,512] = A_bf16[8192,512] @ W[512,512]. BM=128 BN=128 BK=64, 4 waves,
// each wave 32 rows x 128 cols (2x8 16-tiles). Swizzled pitch-64 LDS.
template <bool HEADS>
__global__ __launch_bounds__(256, 3) void gemm_k(
    const unsigned short* __restrict__ A0, size_t zstride,
    const unsigned short* __restrict__ wt, unsigned short* __restrict__ oh,
    float* __restrict__ olin) {
  __shared__ unsigned short As[128 * 64];
  __shared__ unsigned short Bs[128 * 64];
  const int z = blockIdx.z;
  const unsigned short* A = A0 + zstride * z;
  const unsigned short* Wt = wt + (size_t)z * 512 * 512;
  const float scale = (HEADS && z == 0) ? 0.125f * 1.44269504088896f : 1.0f;
  const int m0 = blockIdx.x * 128, n0 = blockIdx.y * 128;
  const int t = threadIdx.x, w = t >> 6, l = t & 63;
  const int quad = l >> 4, c = l & 15;

  f32x4 acc[2][8] = {};

  for (int k0 = 0; k0 < 512; k0 += 64) {
    __syncthreads();
    for (int j = 0; j < 4; ++j) {
      int i = t + j * 256;             // 1024 us8 = 128x64
      int r = i >> 3, u = i & 7;
      *(us8*)&As[r * 64 + ((u ^ (r & 7)) << 3)] =
          *(const us8*)&A[(size_t)(m0 + r) * 512 + k0 + (u << 3)];
      *(us8*)&Bs[r * 64 + ((u ^ (r & 7)) << 3)] =
          *(const us8*)&Wt[(size_t)(n0 + r) * 512 + k0 + (u << 3)];
    }
    __syncthreads();

#pragma unroll
    for (int kc = 0; kc < 2; ++kc) {
      bf16x8 aA[2], bB[8];
      int u = kc * 4 + quad;
#pragma unroll
      for (int mt = 0; mt < 2; ++mt) {
        int row = w * 32 + mt * 16 + c;
        aA[mt] = *(const bf16x8*)&As[row * 64 + ((u ^ (row & 7)) << 3)];
      }
#pragma unroll
      for (int nt = 0; nt < 8; ++nt) {
        int row = nt * 16 + c;
        bB[nt] = *(const bf16x8*)&Bs[row * 64 + ((u ^ (row & 7)) << 3)];
      }
#pragma unroll
      for (int mt = 0; mt < 2; ++mt)
#pragma unroll
        for (int nt = 0; nt < 8; ++nt)
          acc[mt][nt] = __builtin_amdgcn_mfma_f32_16x16x32_bf16(
              aA[mt], bB[nt], acc[mt][nt], 0, 0, 0);
    }
  }

#pragma unroll
  for (int mt = 0; mt < 2; ++mt)
#pragma unroll
    for (int nt = 0; nt < 8; ++nt)
#pragma unroll
      for (int r = 0; r < 4; ++r) {
        int m = m0 + w * 32 + mt * 16 + (quad << 2) + r;
        int n = n0 + nt * 16 + c;
        float val = acc[mt][nt][r] * scale;
        if constexpr (HEADS) {
          int b = m >> 12, s = m & 4095, h = n >> 6, dk = n & 63;
          unsigned short bits =
              (z == 2) ? __builtin_bit_cast(unsigned short, (_Float16)val)
                       : f2bf(val);
          oh[(size_t)z * (Bn * Hn * Sn * DKn) +
             ((size_t)(b * Hn + h) * Sn + s) * DKn + dk] = bits;
        } else {
          olin[(size_t)m * 512 + n] = val;
        }
      }
}

// ------------------------------------------------------------- flash attn
// S^T = K.Q^T (bf16 16x16x32); P stays in REGISTERS (S^T C-frag == A-frag of
// 16x16x16); O = P.V via f16 16x16x16 with V^T staged in LDS. 8 waves x 16 q.
__global__ __launch_bounds__(512, 4) void flash_k(
    const unsigned short* __restrict__ Qh, const unsigned short* __restrict__ Kh,
    const unsigned short* __restrict__ VtG, const unsigned int* __restrict__ pmt,
    unsigned short* __restrict__ attn) {
  __shared__ unsigned short Ks[64 * 64];   // [kv][d], 16B-unit swizzle ^(row&7)
  __shared__ unsigned short Vts[64 * 64];  // [dk][kv] f16, 8B-unit swizzle ^(dk&14)
  __shared__ unsigned int Mw[256];         // [kvw 0..1][q 0..127]

  const int q0 = blockIdx.x * 128, h = blockIdx.y, b = blockIdx.z;
  const int t = threadIdx.x, w = t >> 6, l = t & 63;
  const int quad = l >> 4, c = l & 15;
  const size_t hb = (size_t)(b * Hn + h) * Sn * DKn;
  const unsigned short* Qg = Qh + hb;
  const unsigned short* Kg = Kh + hb;
  const unsigned short* Vg = VtG + hb;     // [dk][s] f16

  // Q fragments (B-operand of S^T): lane holds Q[q = w*16+c][d = kc*32+quad*8+j]
  bf16x8 bQ[2];
  {
    int qrow = q0 + w * 16 + c;
#pragma unroll
    for (int kc = 0; kc < 2; ++kc)
      bQ[kc] = *(const bf16x8*)&Qg[(size_t)qrow * 64 + kc * 32 + quad * 8];
  }

  f32x4 oacc[4] = {};                      // O[q=quad*4+r][dk=dkt*16+c]
  float lsum = 0.f;                        // partial row-sum for q=c (this quad's kv)

  const int sr = t >> 3, su = t & 7;       // staging: row, 16B-unit

  for (int kv0 = 0; kv0 < Sn; kv0 += 64) {
    __syncthreads();
    *(us8*)&Ks[sr * 64 + ((su ^ (sr & 7)) << 3)] =
        *(const us8*)&Kg[(size_t)(kv0 + sr) * 64 + (su << 3)];
    *(us8*)&Vts[sr * 64 + ((((su << 1)) ^ (sr & 14)) << 2)] =
        *(const us8*)&Vg[(size_t)sr * Sn + kv0 + (su << 3)];
    if (t < 256)
      Mw[t] = pmt[((size_t)b * 128 + (kv0 >> 5) + (t >> 7)) * 4096 + q0 + (t & 127)];
    __syncthreads();

    // ---- S^T = K . Q^T : 4 kv-tiles of 16
    f32x4 sacc[4] = {};
#pragma unroll
    for (int kc = 0; kc < 2; ++kc) {
      int u = kc * 4 + quad;
#pragma unroll
      for (int kvt = 0; kvt < 4; ++kvt) {
        int row = kvt * 16 + c;
        bf16x8 aK = *(const bf16x8*)&Ks[row * 64 + ((u ^ (row & 7)) << 3)];
        sacc[kvt] = __builtin_amdgcn_mfma_f32_16x16x32_bf16(
            aK, bQ[kc], sacc[kvt], 0, 0, 0);
      }
    }

    unsigned mv0 = Mw[w * 16 + c];
    unsigned mv1 = Mw[128 + w * 16 + c];

    // ---- masked exp2 -> P-frag (registers) -> O += P.V
#pragma unroll
    for (int kvt = 0; kvt < 4; ++kvt) {
      unsigned word = (kvt & 2) ? mv1 : mv0;
      unsigned bits = (word >> (((kvt & 1) << 4) + (quad << 2))) & 15u;
      f16x4 pb;
      float ps = 0.f;
#pragma unroll
      for (int r = 0; r < 4; ++r) {
        float p = ((bits >> r) & 1u) ? __builtin_amdgcn_exp2f(sacc[kvt][r]) : 0.f;
        ps += p;
        pb[r] = (_Float16)p;
      }
      lsum += ps;
#pragma unroll
      for (int dkt = 0; dkt < 4; ++dkt) {
        int dk = dkt * 16 + c;
        f16x4 bV = *(const f16x4*)&Vts[dk * 64 +
                                       (((kvt * 4 + quad) ^ (dk & 14)) << 2)];
        oacc[dkt] = __builtin_amdgcn_mfma_f32_16x16x16f16(
            pb, bV, oacc[dkt], 0, 0, 0);
      }
    }
  }

  // total row-sum for q=c: combine quads; then fetch inv for q=quad*4+r
  lsum += __shfl_xor(lsum, 16, 64);
  lsum += __shfl_xor(lsum, 32, 64);
  float inv = 1.0f / lsum;
  float invr[4];
#pragma unroll
  for (int r = 0; r < 4; ++r) invr[r] = __shfl(inv, (quad << 2) + r, 64);

  // store: row q0 + w*16 + quad*4 + r, col h*64 + dkt*16 + c (32B segments)
#pragma unroll
  for (int r = 0; r < 4; ++r) {
    unsigned short* dst =
        &attn[((size_t)(b * Sn + q0 + w * 16 + (quad << 2) + r)) * Dn + h * 64 + c];
#pragma unroll
    for (int dkt = 0; dkt < 4; ++dkt)
      dst[dkt * 16] = f2bf(oacc[dkt][r] * invr[r]);
  }
}

// ------------------------------------------------------------------ launch
extern "C" void kernel_launch(void* const* d_in, const int* in_sizes, int n_in,
                              void* d_out, int out_size, void* d_ws,
                              size_t ws_size, hipStream_t stream) {
  const float* q = (const float*)d_in[0];
  const float* k = (const float*)d_in[1];
  const float* v = (const float*)d_in[2];
  const int* mask = (const int*)d_in[3];
  const float* wq = (const float*)d_in[4];
  const float* wk = (const float*)d_in[5];
  const float* wv = (const float*)d_in[6];
  const float* wo = (const float*)d_in[7];
  float* out = (float*)d_out;

  char* ws = (char*)d_ws;
  const size_t headN = (size_t)Bn * Hn * Sn * DKn;        // 4,194,304 elems
  const size_t tensB = headN * 2;                          // 8 MB
  // region A: qb/kb/vb bf16 (3*tensB); after proj consumed: vtg, attn
  unsigned short* qbkb = (unsigned short*)ws;
  unsigned short* vtg  = (unsigned short*)ws;              // reuse post-gemm
  unsigned short* attn = (unsigned short*)(ws + tensB);    // reuse post-gemm
  size_t off = 3 * tensB;
  unsigned short* qkv = (unsigned short*)(ws + off);       // 3*tensB
  off += 3 * tensB;
  unsigned short* wt = (unsigned short*)(ws + off);        // 2 MB
  off += 4ull * 512 * 512 * 2;
  unsigned int* pm = (unsigned int*)(ws + off);            // 4 MB transposed

  pack_mask_k<<<(Bn * Sn * Sn) / 256, 256, 0, stream>>>(mask, pm);
  cvt_k<<<dim3(4096, 3), 256, 0, stream>>>(q, k, v, qbkb);
  wt_k<<<dim3(8, 8, 4), 256, 0, stream>>>(wq, wk, wv, wo, wt);
  gemm_k<true><<<dim3(64, 4, 3), 256, 0, stream>>>(qbkb, headN, wt, qkv, nullptr);
  vt_k<<<dim3(Sn / 64, Bn * Hn), 256, 0, stream>>>(qkv + 2 * headN, vtg);
  flash_k<<<dim3(32, 8, 2), 512, 0, stream>>>(qkv, qkv + headN, vtg, pm, attn);
  gemm_k<false><<<dim3(64, 4, 1), 256, 0, stream>>>(
      attn, 0, wt + 3ull * 512 * 512, nullptr, out);
}

// Round 4
// 420.222 us; speedup vs baseline: 1.3020x; 1.0434x over previous
//
#include <hip/hip_runtime.h>
#include <hip/hip_bf16.h>

#define Bn 2
#define Sn 4096
#define Dn 512
#define Hn 8
#define DKn 64

typedef __attribute__((ext_vector_type(8))) short bf16x8;
typedef __attribute__((ext_vector_type(4))) float f32x4;
typedef __attribute__((ext_vector_type(4))) _Float16 f16x4;
typedef __attribute__((ext_vector_type(8))) unsigned short us8;
typedef __attribute__((ext_vector_type(4))) unsigned short us4;

__device__ __forceinline__ unsigned short f2bf(float f) {
  unsigned u = __builtin_bit_cast(unsigned, f);
  u += 0x7fffu + ((u >> 16) & 1u);   // RNE; inputs finite
  return (unsigned short)(u >> 16);
}

// ---------------------------------------------------------------- pack mask
// 32:1 compress, output TRANSPOSED: pm[b][kvw][q] so flash staging coalesces.
__global__ __launch_bounds__(256) void pack_mask_k(const int* __restrict__ mask,
                                                   unsigned int* __restrict__ pm) {
  int gid = blockIdx.x * 256 + threadIdx.x;
  int m = mask[gid];
  unsigned long long bal = __ballot(m != 0);
  if ((threadIdx.x & 63) == 0) {
    int q = (gid >> 12) & 4095;
    int b = gid >> 24;
    int kvw = (gid >> 5) & 127;
    pm[((size_t)b * 128 + kvw) * 4096 + q] = (unsigned)bal;
    pm[((size_t)b * 128 + kvw + 1) * 4096 + q] = (unsigned)(bal >> 32);
  }
}

// ------------------------------------------------------- fp32 -> bf16 copy
__global__ __launch_bounds__(256) void cvt_k(const float* __restrict__ q,
                                             const float* __restrict__ k,
                                             const float* __restrict__ v,
                                             unsigned short* __restrict__ o) {
  const float* src = blockIdx.y == 0 ? q : blockIdx.y == 1 ? k : v;
  size_t i = (size_t)blockIdx.x * 256 + threadIdx.x;
  float4 f = *(const float4*)&src[i * 4];
  us4 r = {f2bf(f.x), f2bf(f.y), f2bf(f.z), f2bf(f.w)};
  *(us4*)&o[(size_t)blockIdx.y * (Bn * Sn * Dn) + i * 4] = r;
}

// ---------------------------------------------------- weights -> bf16, W^T
__global__ __launch_bounds__(256) void wt_k(const float* __restrict__ wq,
                                            const float* __restrict__ wk,
                                            const float* __restrict__ wv,
                                            const float* __restrict__ wo,
                                            unsigned short* __restrict__ wt) {
  __shared__ unsigned short ls[64][68];
  const float* W = blockIdx.z == 0 ? wq : blockIdx.z == 1 ? wk
                 : blockIdx.z == 2 ? wv : wo;
  int k0 = blockIdx.x * 64, n0 = blockIdx.y * 64;
  int t = threadIdx.x;
  for (int j = 0; j < 4; ++j) {
    int i = t + j * 256;
    int r = i >> 4, c4 = (i & 15) << 2;
    float4 f = *(const float4*)&W[(size_t)(k0 + r) * 512 + n0 + c4];
    ls[c4 + 0][r] = f2bf(f.x);
    ls[c4 + 1][r] = f2bf(f.y);
    ls[c4 + 2][r] = f2bf(f.z);
    ls[c4 + 3][r] = f2bf(f.w);
  }
  __syncthreads();
  unsigned short* out = wt + (size_t)blockIdx.z * 512 * 512;
  for (int j = 0; j < 4; ++j) {
    int i = t + j * 256;
    int r = i >> 4, c4 = (i & 15) << 2;
    us4 v = {ls[r][c4], ls[r][c4 + 1], ls[r][c4 + 2], ls[r][c4 + 3]};
    *(us4*)&out[(size_t)(n0 + r) * 512 + k0 + c4] = v;
  }
}

// ------------------------------------------------------------------- GEMM
// C[8192,512] = A_bf16[8192,512] @ W[512,512]. BM=MT*64, BN=128, BK=64,
// 4 waves, register-prefetch double-buffered staging.
// HEADS: z<2 -> bf16 heads [b,h,s,dk] (Q scaled); z==2 -> f16 V^T permuted
// [bh][dk][blk64: pos(kv)] with pos = ((kv>>5)&1)*32+((kv>>2)&3)*8+((kv>>4)&1)*4+(kv&3)
template <int MT, bool HEADS>
__global__ __launch_bounds__(256, 2) void gemm_k(
    const unsigned short* __restrict__ A0, size_t zstride,
    const unsigned short* __restrict__ wt, unsigned short* __restrict__ oh,
    unsigned short* __restrict__ vtg, float* __restrict__ olin) {
  __shared__ unsigned short As[MT * 64 * 64];
  __shared__ unsigned short Bs[128 * 64];
  const int z = blockIdx.z;
  const unsigned short* A = A0 + zstride * z;
  const unsigned short* Wt = wt + (size_t)z * 512 * 512;
  const float scale = (HEADS && z == 0) ? 0.125f * 1.44269504088896f : 1.0f;
  const int m0 = blockIdx.x * (MT * 64), n0 = blockIdx.y * 128;
  const int t = threadIdx.x, w = t >> 6, l = t & 63;
  const int quad = l >> 4, c = l & 15;

  f32x4 acc[MT][8] = {};

  us8 apre[MT * 2], bpre[4];
#pragma unroll
  for (int j = 0; j < MT * 2; ++j) {
    int i = t + j * 256, r = i >> 3, u = i & 7;
    apre[j] = *(const us8*)&A[(size_t)(m0 + r) * 512 + (u << 3)];
  }
#pragma unroll
  for (int j = 0; j < 4; ++j) {
    int i = t + j * 256, r = i >> 3, u = i & 7;
    bpre[j] = *(const us8*)&Wt[(size_t)(n0 + r) * 512 + (u << 3)];
  }

  for (int k0 = 0; k0 < 512; k0 += 64) {
    __syncthreads();
#pragma unroll
    for (int j = 0; j < MT * 2; ++j) {
      int i = t + j * 256, r = i >> 3, u = i & 7;
      *(us8*)&As[r * 64 + ((u ^ (r & 7)) << 3)] = apre[j];
    }
#pragma unroll
    for (int j = 0; j < 4; ++j) {
      int i = t + j * 256, r = i >> 3, u = i & 7;
      *(us8*)&Bs[r * 64 + ((u ^ (r & 7)) << 3)] = bpre[j];
    }
    __syncthreads();
    if (k0 + 64 < 512) {
#pragma unroll
      for (int j = 0; j < MT * 2; ++j) {
        int i = t + j * 256, r = i >> 3, u = i & 7;
        apre[j] = *(const us8*)&A[(size_t)(m0 + r) * 512 + k0 + 64 + (u << 3)];
      }
#pragma unroll
      for (int j = 0; j < 4; ++j) {
        int i = t + j * 256, r = i >> 3, u = i & 7;
        bpre[j] = *(const us8*)&Wt[(size_t)(n0 + r) * 512 + k0 + 64 + (u << 3)];
      }
    }

#pragma unroll
    for (int kc = 0; kc < 2; ++kc) {
      bf16x8 aA[MT], bB[8];
      int u = kc * 4 + quad;
#pragma unroll
      for (int mt = 0; mt < MT; ++mt) {
        int row = w * (MT * 16) + mt * 16 + c;
        aA[mt] = *(const bf16x8*)&As[row * 64 + ((u ^ (c & 7)) << 3)];
      }
#pragma unroll
      for (int nt = 0; nt < 8; ++nt) {
        int row = nt * 16 + c;
        bB[nt] = *(const bf16x8*)&Bs[row * 64 + ((u ^ (c & 7)) << 3)];
      }
#pragma unroll
      for (int mt = 0; mt < MT; ++mt)
#pragma unroll
        for (int nt = 0; nt < 8; ++nt)
          acc[mt][nt] = __builtin_amdgcn_mfma_f32_16x16x32_bf16(
              aA[mt], bB[nt], acc[mt][nt], 0, 0, 0);
    }
  }

#pragma unroll
  for (int mt = 0; mt < MT; ++mt)
#pragma unroll
    for (int nt = 0; nt < 8; ++nt)
#pragma unroll
      for (int r = 0; r < 4; ++r) {
        int m = m0 + w * (MT * 16) + mt * 16 + (quad << 2) + r;
        int n = n0 + nt * 16 + c;
        float val = acc[mt][nt][r] * scale;
        if constexpr (HEADS) {
          int b = m >> 12, s = m & 4095, h = n >> 6, dk = n & 63;
          if (z < 2) {
            oh[(size_t)z * (Bn * Hn * Sn * DKn) +
               ((size_t)(b * Hn + h) * Sn + s) * DKn + dk] = f2bf(val);
          } else {
            int sl = s & 63;
            int pos = (((sl >> 5) & 1) << 5) | (((sl >> 2) & 3) << 3) |
                      (((sl >> 4) & 1) << 2) | (sl & 3);
            vtg[((size_t)(b * Hn + h) * DKn + dk) * Sn + (s & ~63) + pos] =
                __builtin_bit_cast(unsigned short, (_Float16)val);
          }
        } else {
          olin[(size_t)m * 512 + n] = val;
        }
      }
}

// ------------------------------------------------------------- flash attn
// 256 thr, 4 waves x 32 q. S^T = K.Q^T (bf16 16x16x32, C-frag == A-frag of
// 16x16x16); O = P.V via f16 16x16x16, V^T pre-permuted so one b128 yields
// both kvt B-frags. Register-prefetch double-buffered staging.
__global__ __launch_bounds__(256, 2) void flash_k(
    const unsigned short* __restrict__ Qh, const unsigned short* __restrict__ Kh,
    const unsigned short* __restrict__ VtG, const unsigned int* __restrict__ pmt,
    unsigned short* __restrict__ attn) {
  __shared__ unsigned short Ks[64 * 64];   // [kv][d], 16B-unit swizzle ^(row&7)
  __shared__ unsigned short Vts[64 * 64];  // [dk][pos(kv)] f16, same swizzle
  __shared__ unsigned int Mw[256];         // [kvw 0..1][q 0..127]

  const int q0 = blockIdx.x * 128, h = blockIdx.y, b = blockIdx.z;
  const int t = threadIdx.x, w = t >> 6, l = t & 63;
  const int quad = l >> 4, c = l & 15;
  const size_t hb = (size_t)(b * Hn + h) * Sn * DKn;
  const unsigned short* Qg = Qh + hb;
  const unsigned short* Kg = Kh + hb;
  const unsigned short* Vg = VtG + hb;     // [dk][s] f16 (permuted per 64-blk)

  // Q B-frags: lane holds Q[q = w*32+qf*16+c][d = kc*32+quad*8+j]
  bf16x8 bQ[2][2];
#pragma unroll
  for (int qf = 0; qf < 2; ++qf) {
    int qrow = q0 + w * 32 + qf * 16 + c;
#pragma unroll
    for (int kc = 0; kc < 2; ++kc)
      bQ[qf][kc] = *(const bf16x8*)&Qg[(size_t)qrow * 64 + kc * 32 + quad * 8];
  }

  f32x4 oacc[2][4] = {};
  float lsum[2] = {};
  const int sr = t >> 3, su = t & 7;

  us8 kpre[2], vpre[2];
  unsigned mpre;
#pragma unroll
  for (int j = 0; j < 2; ++j) {
    kpre[j] = *(const us8*)&Kg[(size_t)(sr + j * 32) * 64 + (su << 3)];
    vpre[j] = *(const us8*)&Vg[(size_t)(sr + j * 32) * Sn + (su << 3)];
  }
  mpre = pmt[((size_t)b * 128 + (t >> 7)) * 4096 + q0 + (t & 127)];

  for (int kv0 = 0; kv0 < Sn; kv0 += 64) {
    __syncthreads();
#pragma unroll
    for (int j = 0; j < 2; ++j) {
      int r = sr + j * 32;
      *(us8*)&Ks[r * 64 + ((su ^ (r & 7)) << 3)] = kpre[j];
      *(us8*)&Vts[r * 64 + ((su ^ (r & 7)) << 3)] = vpre[j];
    }
    Mw[t] = mpre;
    __syncthreads();
    if (kv0 + 64 < Sn) {
#pragma unroll
      for (int j = 0; j < 2; ++j) {
        kpre[j] = *(const us8*)&Kg[(size_t)(kv0 + 64 + sr + j * 32) * 64 + (su << 3)];
        vpre[j] = *(const us8*)&Vg[(size_t)(sr + j * 32) * Sn + kv0 + 64 + (su << 3)];
      }
      mpre = pmt[((size_t)b * 128 + ((kv0 + 64) >> 5) + (t >> 7)) * 4096 +
                 q0 + (t & 127)];
    }

    // ---- S^T = K . Q^T
    f32x4 sacc[2][4] = {};
#pragma unroll
    for (int kc = 0; kc < 2; ++kc) {
      int u = kc * 4 + quad;
#pragma unroll
      for (int kvt = 0; kvt < 4; ++kvt) {
        int row = kvt * 16 + c;
        bf16x8 aK = *(const bf16x8*)&Ks[row * 64 + ((u ^ (c & 7)) << 3)];
#pragma unroll
        for (int qf = 0; qf < 2; ++qf)
          sacc[qf][kvt] = __builtin_amdgcn_mfma_f32_16x16x32_bf16(
              aK, bQ[qf][kc], sacc[qf][kvt], 0, 0, 0);
      }
    }

    // ---- masked exp2 -> P-frags (registers)
    f16x4 pb[2][4];
#pragma unroll
    for (int qf = 0; qf < 2; ++qf) {
      int qloc = w * 32 + qf * 16 + c;
      unsigned mv0 = Mw[qloc], mv1 = Mw[128 + qloc];
#pragma unroll
      for (int kvt = 0; kvt < 4; ++kvt) {
        unsigned word = (kvt & 2) ? mv1 : mv0;
        unsigned bits = (word >> (((kvt & 1) << 4) + (quad << 2))) & 15u;
        float ps = 0.f;
#pragma unroll
        for (int r = 0; r < 4; ++r) {
          float p = ((bits >> r) & 1u) ? __builtin_amdgcn_exp2f(sacc[qf][kvt][r])
                                       : 0.f;
          ps += p;
          pb[qf][kvt][r] = (_Float16)p;
        }
        lsum[qf] += ps;
      }
    }

    // ---- O += P.V  (one b128 -> both kvt B-frags of a 32-kv half)
#pragma unroll
    for (int kp = 0; kp < 2; ++kp) {
#pragma unroll
      for (int dkt = 0; dkt < 4; ++dkt) {
        int dk = dkt * 16 + c;
        us8 vv = *(const us8*)&Vts[dk * 64 + (((kp * 4 + quad) ^ (c & 7)) << 3)];
        f16x4 lo = __builtin_bit_cast(f16x4, (us4){vv[0], vv[1], vv[2], vv[3]});
        f16x4 hi = __builtin_bit_cast(f16x4, (us4){vv[4], vv[5], vv[6], vv[7]});
#pragma unroll
        for (int qf = 0; qf < 2; ++qf) {
          oacc[qf][dkt] = __builtin_amdgcn_mfma_f32_16x16x16f16(
              pb[qf][kp * 2], lo, oacc[qf][dkt], 0, 0, 0);
          oacc[qf][dkt] = __builtin_amdgcn_mfma_f32_16x16x16f16(
              pb[qf][kp * 2 + 1], hi, oacc[qf][dkt], 0, 0, 0);
        }
      }
    }
  }

  // epilogue: combine quad partials, normalize, merged-head store
#pragma unroll
  for (int qf = 0; qf < 2; ++qf) {
    float s = lsum[qf];
    s += __shfl_xor(s, 16, 64);
    s += __shfl_xor(s, 32, 64);
    float inv = 1.0f / s;
#pragma unroll
    for (int r = 0; r < 4; ++r) {
      float invr = __shfl(inv, (quad << 2) + r, 64);
      unsigned short* dst =
          &attn[((size_t)(b * Sn + q0 + w * 32 + qf * 16 + (quad << 2) + r)) * Dn +
                h * 64 + c];
#pragma unroll
      for (int dkt = 0; dkt < 4; ++dkt)
        dst[dkt * 16] = f2bf(oacc[qf][dkt][r] * invr);
    }
  }
}

// ------------------------------------------------------------------ launch
extern "C" void kernel_launch(void* const* d_in, const int* in_sizes, int n_in,
                              void* d_out, int out_size, void* d_ws,
                              size_t ws_size, hipStream_t stream) {
  const float* q = (const float*)d_in[0];
  const float* k = (const float*)d_in[1];
  const float* v = (const float*)d_in[2];
  const int* mask = (const int*)d_in[3];
  const float* wq = (const float*)d_in[4];
  const float* wk = (const float*)d_in[5];
  const float* wv = (const float*)d_in[6];
  const float* wo = (const float*)d_in[7];
  float* out = (float*)d_out;

  char* ws = (char*)d_ws;
  const size_t headN = (size_t)Bn * Hn * Sn * DKn;        // 4,194,304 elems
  const size_t tensB = headN * 2;                          // 8 MB
  // [0:24M) qb/kb/vb bf16; attn reuses [0:8M) after proj consumes qbkb
  unsigned short* qbkb = (unsigned short*)ws;
  unsigned short* attn = (unsigned short*)ws;              // reuse post-proj
  size_t off = 3 * tensB;
  unsigned short* qkv = (unsigned short*)(ws + off);       // Q,K heads + V^T
  off += 3 * tensB;
  unsigned short* wt = (unsigned short*)(ws + off);        // 2 MB
  off += 4ull * 512 * 512 * 2;
  unsigned int* pm = (unsigned int*)(ws + off);            // 4 MB transposed

  pack_mask_k<<<(Bn * Sn * Sn) / 256, 256, 0, stream>>>(mask, pm);
  cvt_k<<<dim3(4096, 3), 256, 0, stream>>>(q, k, v, qbkb);
  wt_k<<<dim3(8, 8, 4), 256, 0, stream>>>(wq, wk, wv, wo, wt);
  gemm_k<2, true><<<dim3(64, 4, 3), 256, 0, stream>>>(
      qbkb, headN, wt, qkv, qkv + 2 * headN, nullptr);
  flash_k<<<dim3(32, 8, 2), 256, 0, stream>>>(qkv, qkv + headN,
                                              qkv + 2 * headN, pm, attn);
  gemm_k<1, false><<<dim3(128, 4, 1), 256, 0, stream>>>(
      attn, 0, wt + 3ull * 512 * 512, nullptr, nullptr, out);
}

// Round 5
// 409.383 us; speedup vs baseline: 1.3365x; 1.0265x over previous
//
#include <hip/hip_runtime.h>
#include <hip/hip_bf16.h>

#define Bn 2
#define Sn 4096
#define Dn 512
#define Hn 8
#define DKn 64

typedef __attribute__((ext_vector_type(8))) short bf16x8;
typedef __attribute__((ext_vector_type(4))) float f32x4;
typedef __attribute__((ext_vector_type(4))) _Float16 f16x4;
typedef __attribute__((ext_vector_type(8))) unsigned short us8;
typedef __attribute__((ext_vector_type(4))) unsigned short us4;

__device__ __forceinline__ unsigned short f2bf(float f) {
  unsigned u = __builtin_bit_cast(unsigned, f);
  u += 0x7fffu + ((u >> 16) & 1u);   // RNE; inputs finite
  return (unsigned short)(u >> 16);
}

// ---------------------------------------------------------------- pack mask
// 32:1 compress, output TRANSPOSED: pm[b][kvw][q] so flash staging coalesces.
__global__ __launch_bounds__(256) void pack_mask_k(const int* __restrict__ mask,
                                                   unsigned int* __restrict__ pm) {
  int gid = blockIdx.x * 256 + threadIdx.x;
  int m = mask[gid];
  unsigned long long bal = __ballot(m != 0);
  if ((threadIdx.x & 63) == 0) {
    int q = (gid >> 12) & 4095;
    int b = gid >> 24;
    int kvw = (gid >> 5) & 127;
    pm[((size_t)b * 128 + kvw) * 4096 + q] = (unsigned)bal;
    pm[((size_t)b * 128 + kvw + 1) * 4096 + q] = (unsigned)(bal >> 32);
  }
}

// ------------------------------------------------------- fp32 -> bf16 copy
__global__ __launch_bounds__(256) void cvt_k(const float* __restrict__ q,
                                             const float* __restrict__ k,
                                             const float* __restrict__ v,
                                             unsigned short* __restrict__ o) {
  const float* src = blockIdx.y == 0 ? q : blockIdx.y == 1 ? k : v;
  size_t i = (size_t)blockIdx.x * 256 + threadIdx.x;
  float4 f = *(const float4*)&src[i * 4];
  us4 r = {f2bf(f.x), f2bf(f.y), f2bf(f.z), f2bf(f.w)};
  *(us4*)&o[(size_t)blockIdx.y * (Bn * Sn * Dn) + i * 4] = r;
}

// ---------------------------------------------------- weights -> bf16, W^T
__global__ __launch_bounds__(256) void wt_k(const float* __restrict__ wq,
                                            const float* __restrict__ wk,
                                            const float* __restrict__ wv,
                                            const float* __restrict__ wo,
                                            unsigned short* __restrict__ wt) {
  __shared__ unsigned short ls[64][68];
  const float* W = blockIdx.z == 0 ? wq : blockIdx.z == 1 ? wk
                 : blockIdx.z == 2 ? wv : wo;
  int k0 = blockIdx.x * 64, n0 = blockIdx.y * 64;
  int t = threadIdx.x;
  for (int j = 0; j < 4; ++j) {
    int i = t + j * 256;
    int r = i >> 4, c4 = (i & 15) << 2;
    float4 f = *(const float4*)&W[(size_t)(k0 + r) * 512 + n0 + c4];
    ls[c4 + 0][r] = f2bf(f.x);
    ls[c4 + 1][r] = f2bf(f.y);
    ls[c4 + 2][r] = f2bf(f.z);
    ls[c4 + 3][r] = f2bf(f.w);
  }
  __syncthreads();
  unsigned short* out = wt + (size_t)blockIdx.z * 512 * 512;
  for (int j = 0; j < 4; ++j) {
    int i = t + j * 256;
    int r = i >> 4, c4 = (i & 15) << 2;
    us4 v = {ls[r][c4], ls[r][c4 + 1], ls[r][c4 + 2], ls[r][c4 + 3]};
    *(us4*)&out[(size_t)(n0 + r) * 512 + k0 + c4] = v;
  }
}

// ------------------------------------------------------------------- GEMM
// C[8192,512] = A_bf16[8192,512] @ W[512,512]. BM=MT*64, BN=128, BK=64,
// 4 waves, LDS double-buffered K-loop with ONE barrier per k-tile.
// HEADS: z<2 -> bf16 heads [b,h,s,dk] (Q scaled); z==2 -> f16 V^T permuted,
// written via in-LDS transpose (coalesced 256B runs).
template <int MT, bool HEADS>
__global__ __launch_bounds__(256, 2) void gemm_k(
    const unsigned short* __restrict__ A0, size_t zstride,
    const unsigned short* __restrict__ wt, unsigned short* __restrict__ oh,
    unsigned short* __restrict__ vtg, float* __restrict__ olin) {
  __shared__ unsigned short smem[MT * 8192 + 16384];  // As[2] | Bs[2]
  const int z = blockIdx.z;
  const unsigned short* A = A0 + zstride * z;
  const unsigned short* Wt = wt + (size_t)z * 512 * 512;
  const float scale = (HEADS && z == 0) ? 0.125f * 1.44269504088896f : 1.0f;
  const int m0 = blockIdx.x * (MT * 64), n0 = blockIdx.y * 128;
  const int t = threadIdx.x, w = t >> 6, l = t & 63;
  const int quad = l >> 4, c = l & 15;

  f32x4 acc[MT][8] = {};
  us8 apre[MT * 2], bpre[4];

#pragma unroll
  for (int j = 0; j < MT * 2; ++j) {
    int i = t + j * 256, r = i >> 3, u = i & 7;
    apre[j] = *(const us8*)&A[(size_t)(m0 + r) * 512 + (u << 3)];
  }
#pragma unroll
  for (int j = 0; j < 4; ++j) {
    int i = t + j * 256, r = i >> 3, u = i & 7;
    bpre[j] = *(const us8*)&Wt[(size_t)(n0 + r) * 512 + (u << 3)];
  }
#pragma unroll
  for (int j = 0; j < MT * 2; ++j) {   // stage buf 0
    int i = t + j * 256, r = i >> 3, u = i & 7;
    *(us8*)&smem[r * 64 + ((u ^ (r & 7)) << 3)] = apre[j];
  }
#pragma unroll
  for (int j = 0; j < 4; ++j) {
    int i = t + j * 256, r = i >> 3, u = i & 7;
    *(us8*)&smem[MT * 8192 + r * 64 + ((u ^ (r & 7)) << 3)] = bpre[j];
  }

  for (int k0 = 0; k0 < 512; k0 += 64) {
    const int cur = (k0 >> 6) & 1;
    const unsigned short* AsC = &smem[cur * (MT * 4096)];
    const unsigned short* BsC = &smem[MT * 8192 + cur * 8192];
    __syncthreads();
    const bool nxt = k0 + 64 < 512;
    if (nxt) {
#pragma unroll
      for (int j = 0; j < MT * 2; ++j) {
        int i = t + j * 256, r = i >> 3, u = i & 7;
        apre[j] = *(const us8*)&A[(size_t)(m0 + r) * 512 + k0 + 64 + (u << 3)];
      }
#pragma unroll
      for (int j = 0; j < 4; ++j) {
        int i = t + j * 256, r = i >> 3, u = i & 7;
        bpre[j] = *(const us8*)&Wt[(size_t)(n0 + r) * 512 + k0 + 64 + (u << 3)];
      }
    }

#pragma unroll
    for (int kc = 0; kc < 2; ++kc) {
      bf16x8 aA[MT], bB[8];
      int u = kc * 4 + quad;
#pragma unroll
      for (int mt = 0; mt < MT; ++mt) {
        int row = w * (MT * 16) + mt * 16 + c;
        aA[mt] = *(const bf16x8*)&AsC[row * 64 + ((u ^ (c & 7)) << 3)];
      }
#pragma unroll
      for (int nt = 0; nt < 8; ++nt) {
        int row = nt * 16 + c;
        bB[nt] = *(const bf16x8*)&BsC[row * 64 + ((u ^ (c & 7)) << 3)];
      }
#pragma unroll
      for (int mt = 0; mt < MT; ++mt)
#pragma unroll
        for (int nt = 0; nt < 8; ++nt)
          acc[mt][nt] = __builtin_amdgcn_mfma_f32_16x16x32_bf16(
              aA[mt], bB[nt], acc[mt][nt], 0, 0, 0);
    }

    if (nxt) {
      unsigned short* AsN = &smem[(cur ^ 1) * (MT * 4096)];
      unsigned short* BsN = &smem[MT * 8192 + (cur ^ 1) * 8192];
#pragma unroll
      for (int j = 0; j < MT * 2; ++j) {
        int i = t + j * 256, r = i >> 3, u = i & 7;
        *(us8*)&AsN[r * 64 + ((u ^ (r & 7)) << 3)] = apre[j];
      }
#pragma unroll
      for (int j = 0; j < 4; ++j) {
        int i = t + j * 256, r = i >> 3, u = i & 7;
        *(us8*)&BsN[r * 64 + ((u ^ (r & 7)) << 3)] = bpre[j];
      }
    }
  }

  if constexpr (HEADS) {
    if (z == 2) {
      // ---- V^T epilogue via LDS transpose (pitch 152 shorts) ----
      __syncthreads();
#pragma unroll
      for (int mt = 0; mt < MT; ++mt) {
        int mb = w * (MT * 16) + mt * 16 + (quad << 2);   // mb&3 == 0
        int ml = (mb & 64) | (((mb >> 5) & 1) << 5) | (((mb >> 2) & 3) << 3) |
                 (((mb >> 4) & 1) << 2);                  // pos-permuted coord
#pragma unroll
        for (int nt = 0; nt < 8; ++nt) {
          int nl = nt * 16 + c;
          us4 pk;
#pragma unroll
          for (int r = 0; r < 4; ++r)
            pk[r] = __builtin_bit_cast(unsigned short, (_Float16)acc[mt][nt][r]);
          *(us4*)&smem[nl * 152 + ml] = pk;
        }
      }
      __syncthreads();
      const int bb = m0 >> 12, sb = m0 & 4095;
#pragma unroll
      for (int j = 0; j < MT * 4; ++j) {   // MT=2: 2048 us8 chunks
        int i = t + j * 256;
        int nl = i >> 4, mc = (i & 15) << 3;
        us8 vv = *(const us8*)&smem[nl * 152 + mc];
        int n = n0 + nl, hh = n >> 6, dk = n & 63;
        *(us8*)&vtg[((size_t)(bb * Hn + hh) * DKn + dk) * Sn + sb + mc] = vv;
      }
    } else {
#pragma unroll
      for (int mt = 0; mt < MT; ++mt)
#pragma unroll
        for (int nt = 0; nt < 8; ++nt)
#pragma unroll
          for (int r = 0; r < 4; ++r) {
            int m = m0 + w * (MT * 16) + mt * 16 + (quad << 2) + r;
            int n = n0 + nt * 16 + c;
            int b = m >> 12, s = m & 4095, hh = n >> 6, dk = n & 63;
            oh[(size_t)z * (Bn * Hn * Sn * DKn) +
               ((size_t)(b * Hn + hh) * Sn + s) * DKn + dk] =
                f2bf(acc[mt][nt][r] * scale);
          }
    }
  } else {
#pragma unroll
    for (int mt = 0; mt < MT; ++mt)
#pragma unroll
      for (int nt = 0; nt < 8; ++nt)
#pragma unroll
        for (int r = 0; r < 4; ++r) {
          int m = m0 + w * (MT * 16) + mt * 16 + (quad << 2) + r;
          int n = n0 + nt * 16 + c;
          olin[(size_t)m * 512 + n] = acc[mt][nt][r];
        }
  }
}

// ------------------------------------------------------------- flash attn
// 256 thr, 4 waves x 32 q. S^T = K.Q^T; P stays in registers; O = P.V f16.
// LDS double-buffered: ONE __syncthreads per KV tile.
__global__ __launch_bounds__(256, 2) void flash_k(
    const unsigned short* __restrict__ Qh, const unsigned short* __restrict__ Kh,
    const unsigned short* __restrict__ VtG, const unsigned int* __restrict__ pmt,
    unsigned short* __restrict__ attn) {
  __shared__ unsigned short Ks[2][64 * 64];
  __shared__ unsigned short Vts[2][64 * 64];
  __shared__ unsigned int Mw[2][256];

  const int q0 = blockIdx.x * 128, h = blockIdx.y, b = blockIdx.z;
  const int t = threadIdx.x, w = t >> 6, l = t & 63;
  const int quad = l >> 4, c = l & 15;
  const size_t hb = (size_t)(b * Hn + h) * Sn * DKn;
  const unsigned short* Qg = Qh + hb;
  const unsigned short* Kg = Kh + hb;
  const unsigned short* Vg = VtG + hb;     // [dk][s] f16 (permuted per 64-blk)

  bf16x8 bQ[2][2];
#pragma unroll
  for (int qf = 0; qf < 2; ++qf) {
    int qrow = q0 + w * 32 + qf * 16 + c;
#pragma unroll
    for (int kc = 0; kc < 2; ++kc)
      bQ[qf][kc] = *(const bf16x8*)&Qg[(size_t)qrow * 64 + kc * 32 + quad * 8];
  }

  f32x4 oacc[2][4] = {};
  float lsum[2] = {};
  const int sr = t >> 3, su = t & 7;
  const int off0 = sr * 64 + ((su ^ (sr & 7)) << 3);          // rows sr, sr+32:
  const int off1 = (sr + 32) * 64 + ((su ^ (sr & 7)) << 3);   // same xor (32%8==0)

  us8 kpre[2], vpre[2];
  unsigned mpre;
  kpre[0] = *(const us8*)&Kg[(size_t)sr * 64 + (su << 3)];
  kpre[1] = *(const us8*)&Kg[(size_t)(sr + 32) * 64 + (su << 3)];
  vpre[0] = *(const us8*)&Vg[(size_t)sr * Sn + (su << 3)];
  vpre[1] = *(const us8*)&Vg[(size_t)(sr + 32) * Sn + (su << 3)];
  mpre = pmt[((size_t)b * 128 + (t >> 7)) * 4096 + q0 + (t & 127)];
  *(us8*)&Ks[0][off0] = kpre[0];
  *(us8*)&Ks[0][off1] = kpre[1];
  *(us8*)&Vts[0][off0] = vpre[0];
  *(us8*)&Vts[0][off1] = vpre[1];
  Mw[0][t] = mpre;

  for (int kv0 = 0; kv0 < Sn; kv0 += 64) {
    const int cur = (kv0 >> 6) & 1;
    __syncthreads();
    const bool nxt = kv0 + 64 < Sn;
    if (nxt) {
      kpre[0] = *(const us8*)&Kg[(size_t)(kv0 + 64 + sr) * 64 + (su << 3)];
      kpre[1] = *(const us8*)&Kg[(size_t)(kv0 + 96 + sr) * 64 + (su << 3)];
      vpre[0] = *(const us8*)&Vg[(size_t)sr * Sn + kv0 + 64 + (su << 3)];
      vpre[1] = *(const us8*)&Vg[(size_t)(sr + 32) * Sn + kv0 + 64 + (su << 3)];
      mpre = pmt[((size_t)b * 128 + ((kv0 + 64) >> 5) + (t >> 7)) * 4096 +
                 q0 + (t & 127)];
    }

    // ---- S^T = K . Q^T
    f32x4 sacc[2][4] = {};
#pragma unroll
    for (int kc = 0; kc < 2; ++kc) {
      int u = kc * 4 + quad;
#pragma unroll
      for (int kvt = 0; kvt < 4; ++kvt) {
        int row = kvt * 16 + c;
        bf16x8 aK = *(const bf16x8*)&Ks[cur][row * 64 + ((u ^ (c & 7)) << 3)];
#pragma unroll
        for (int qf = 0; qf < 2; ++qf)
          sacc[qf][kvt] = __builtin_amdgcn_mfma_f32_16x16x32_bf16(
              aK, bQ[qf][kc], sacc[qf][kvt], 0, 0, 0);
      }
    }

    // ---- masked exp2 -> P-frags (registers)
    f16x4 pb[2][4];
#pragma unroll
    for (int qf = 0; qf < 2; ++qf) {
      int qloc = w * 32 + qf * 16 + c;
      unsigned mv0 = Mw[cur][qloc], mv1 = Mw[cur][128 + qloc];
#pragma unroll
      for (int kvt = 0; kvt < 4; ++kvt) {
        unsigned word = (kvt & 2) ? mv1 : mv0;
        unsigned bits = (word >> (((kvt & 1) << 4) + (quad << 2))) & 15u;
        float ps = 0.f;
#pragma unroll
        for (int r = 0; r < 4; ++r) {
          float p = ((bits >> r) & 1u) ? __builtin_amdgcn_exp2f(sacc[qf][kvt][r])
                                       : 0.f;
          ps += p;
          pb[qf][kvt][r] = (_Float16)p;
        }
        lsum[qf] += ps;
      }
    }

    // ---- O += P.V  (one b128 -> both kvt B-frags of a 32-kv half)
#pragma unroll
    for (int kp = 0; kp < 2; ++kp) {
#pragma unroll
      for (int dkt = 0; dkt < 4; ++dkt) {
        int dk = dkt * 16 + c;
        us8 vv = *(const us8*)&Vts[cur][dk * 64 +
                                        (((kp * 4 + quad) ^ (c & 7)) << 3)];
        f16x4 lo = __builtin_bit_cast(f16x4, (us4){vv[0], vv[1], vv[2], vv[3]});
        f16x4 hi = __builtin_bit_cast(f16x4, (us4){vv[4], vv[5], vv[6], vv[7]});
#pragma unroll
        for (int qf = 0; qf < 2; ++qf) {
          oacc[qf][dkt] = __builtin_amdgcn_mfma_f32_16x16x16f16(
              pb[qf][kp * 2], lo, oacc[qf][dkt], 0, 0, 0);
          oacc[qf][dkt] = __builtin_amdgcn_mfma_f32_16x16x16f16(
              pb[qf][kp * 2 + 1], hi, oacc[qf][dkt], 0, 0, 0);
        }
      }
    }

    if (nxt) {
      const int nb = cur ^ 1;
      *(us8*)&Ks[nb][off0] = kpre[0];
      *(us8*)&Ks[nb][off1] = kpre[1];
      *(us8*)&Vts[nb][off0] = vpre[0];
      *(us8*)&Vts[nb][off1] = vpre[1];
      Mw[nb][t] = mpre;
    }
  }

  // epilogue: combine quad partials, normalize, merged-head store
#pragma unroll
  for (int qf = 0; qf < 2; ++qf) {
    float s = lsum[qf];
    s += __shfl_xor(s, 16, 64);
    s += __shfl_xor(s, 32, 64);
    float inv = 1.0f / s;
#pragma unroll
    for (int r = 0; r < 4; ++r) {
      float invr = __shfl(inv, (quad << 2) + r, 64);
      unsigned short* dst =
          &attn[((size_t)(b * Sn + q0 + w * 32 + qf * 16 + (quad << 2) + r)) * Dn +
                h * 64 + c];
#pragma unroll
      for (int dkt = 0; dkt < 4; ++dkt)
        dst[dkt * 16] = f2bf(oacc[qf][dkt][r] * invr);
    }
  }
}

// ------------------------------------------------------------------ launch
extern "C" void kernel_launch(void* const* d_in, const int* in_sizes, int n_in,
                              void* d_out, int out_size, void* d_ws,
                              size_t ws_size, hipStream_t stream) {
  const float* q = (const float*)d_in[0];
  const float* k = (const float*)d_in[1];
  const float* v = (const float*)d_in[2];
  const int* mask = (const int*)d_in[3];
  const float* wq = (const float*)d_in[4];
  const float* wk = (const float*)d_in[5];
  const float* wv = (const float*)d_in[6];
  const float* wo = (const float*)d_in[7];
  float* out = (float*)d_out;

  char* ws = (char*)d_ws;
  const size_t headN = (size_t)Bn * Hn * Sn * DKn;        // 4,194,304 elems
  const size_t tensB = headN * 2;                          // 8 MB
  unsigned short* qbkb = (unsigned short*)ws;
  unsigned short* attn = (unsigned short*)ws;              // reuse post-proj
  size_t off = 3 * tensB;
  unsigned short* qkv = (unsigned short*)(ws + off);       // Q,K heads + V^T
  off += 3 * tensB;
  unsigned short* wt = (unsigned short*)(ws + off);        // 2 MB
  off += 4ull * 512 * 512 * 2;
  unsigned int* pm = (unsigned int*)(ws + off);            // 4 MB transposed

  pack_mask_k<<<(Bn * Sn * Sn) / 256, 256, 0, stream>>>(mask, pm);
  cvt_k<<<dim3(4096, 3), 256, 0, stream>>>(q, k, v, qbkb);
  wt_k<<<dim3(8, 8, 4), 256, 0, stream>>>(wq, wk, wv, wo, wt);
  gemm_k<2, true><<<dim3(64, 4, 3), 256, 0, stream>>>(
      qbkb, headN, wt, qkv, qkv + 2 * headN, nullptr);
  flash_k<<<dim3(32, 8, 2), 256, 0, stream>>>(qkv, qkv + headN,
                                              qkv + 2 * headN, pm, attn);
  gemm_k<1, false><<<dim3(128, 4, 1), 256, 0, stream>>>(
      attn, 0, wt + 3ull * 512 * 512, nullptr, nullptr, out);
}

// Round 7
// 388.173 us; speedup vs baseline: 1.4095x; 1.0546x over previous
//
#include <hip/hip_runtime.h>
#include <hip/hip_bf16.h>

#define Bn 2
#define Sn 4096
#define Dn 512
#define Hn 8
#define DKn 64

typedef __attribute__((ext_vector_type(8))) short bf16x8;
typedef __attribute__((ext_vector_type(4))) float f32x4;
typedef __attribute__((ext_vector_type(4))) _Float16 f16x4;
typedef __attribute__((ext_vector_type(8))) _Float16 f16x8;
typedef __attribute__((ext_vector_type(2))) _Float16 f16x2;
typedef __attribute__((ext_vector_type(8))) unsigned short us8;
typedef __attribute__((ext_vector_type(4))) unsigned short us4;

__device__ __forceinline__ unsigned short f2bf(float f) {
  unsigned u = __builtin_bit_cast(unsigned, f);
  u += 0x7fffu + ((u >> 16) & 1u);   // RNE; inputs finite
  return (unsigned short)(u >> 16);
}

// ---------------------------------------------------------------- pack mask
// 32:1 compress, output TRANSPOSED: pm[b][kvw][q] so flash staging coalesces.
__global__ __launch_bounds__(256) void pack_mask_k(const int* __restrict__ mask,
                                                   unsigned int* __restrict__ pm) {
  int gid = blockIdx.x * 256 + threadIdx.x;
  int m = mask[gid];
  unsigned long long bal = __ballot(m != 0);
  if ((threadIdx.x & 63) == 0) {
    int q = (gid >> 12) & 4095;
    int b = gid >> 24;
    int kvw = (gid >> 5) & 127;
    pm[((size_t)b * 128 + kvw) * 4096 + q] = (unsigned)bal;
    pm[((size_t)b * 128 + kvw + 1) * 4096 + q] = (unsigned)(bal >> 32);
  }
}

// ------------------------------------------------------- fp32 -> bf16 copy
__global__ __launch_bounds__(256) void cvt_k(const float* __restrict__ q,
                                             const float* __restrict__ k,
                                             const float* __restrict__ v,
                                             unsigned short* __restrict__ o) {
  const float* src = blockIdx.y == 0 ? q : blockIdx.y == 1 ? k : v;
  size_t i = (size_t)blockIdx.x * 256 + threadIdx.x;
  float4 f = *(const float4*)&src[i * 4];
  us4 r = {f2bf(f.x), f2bf(f.y), f2bf(f.z), f2bf(f.w)};
  *(us4*)&o[(size_t)blockIdx.y * (Bn * Sn * Dn) + i * 4] = r;
}

// ---------------------------------------------------- weights -> bf16, W^T
__global__ __launch_bounds__(256) void wt_k(const float* __restrict__ wq,
                                            const float* __restrict__ wk,
                                            const float* __restrict__ wv,
                                            const float* __restrict__ wo,
                                            unsigned short* __restrict__ wt) {
  __shared__ unsigned short ls[64][68];
  const float* W = blockIdx.z == 0 ? wq : blockIdx.z == 1 ? wk
                 : blockIdx.z == 2 ? wv : wo;
  int k0 = blockIdx.x * 64, n0 = blockIdx.y * 64;
  int t = threadIdx.x;
  for (int j = 0; j < 4; ++j) {
    int i = t + j * 256;
    int r = i >> 4, c4 = (i & 15) << 2;
    float4 f = *(const float4*)&W[(size_t)(k0 + r) * 512 + n0 + c4];
    ls[c4 + 0][r] = f2bf(f.x);
    ls[c4 + 1][r] = f2bf(f.y);
    ls[c4 + 2][r] = f2bf(f.z);
    ls[c4 + 3][r] = f2bf(f.w);
  }
  __syncthreads();
  unsigned short* out = wt + (size_t)blockIdx.z * 512 * 512;
  for (int j = 0; j < 4; ++j) {
    int i = t + j * 256;
    int r = i >> 4, c4 = (i & 15) << 2;
    us4 v = {ls[r][c4], ls[r][c4 + 1], ls[r][c4 + 2], ls[r][c4 + 3]};
    *(us4*)&out[(size_t)(n0 + r) * 512 + k0 + c4] = v;
  }
}

// ------------------------------------------------------------------- GEMM
// C[8192,512] = A_bf16[8192,512] @ W[512,512]. BM=MT*64, BN=128, BK=64,
// 4 waves, LDS double-buffered K-loop with ONE barrier per k-tile.
template <int MT, bool HEADS>
__global__ __launch_bounds__(256, 2) void gemm_k(
    const unsigned short* __restrict__ A0, size_t zstride,
    const unsigned short* __restrict__ wt, unsigned short* __restrict__ oh,
    unsigned short* __restrict__ vtg, float* __restrict__ olin) {
  __shared__ unsigned short smem[MT * 8192 + 16384];  // As[2] | Bs[2]
  const int z = blockIdx.z;
  const unsigned short* A = A0 + zstride * z;
  const unsigned short* Wt = wt + (size_t)z * 512 * 512;
  const float scale = (HEADS && z == 0) ? 0.125f * 1.44269504088896f : 1.0f;
  const int m0 = blockIdx.x * (MT * 64), n0 = blockIdx.y * 128;
  const int t = threadIdx.x, w = t >> 6, l = t & 63;
  const int quad = l >> 4, c = l & 15;

  f32x4 acc[MT][8] = {};
  us8 apre[MT * 2], bpre[4];

#pragma unroll
  for (int j = 0; j < MT * 2; ++j) {
    int i = t + j * 256, r = i >> 3, u = i & 7;
    apre[j] = *(const us8*)&A[(size_t)(m0 + r) * 512 + (u << 3)];
  }
#pragma unroll
  for (int j = 0; j < 4; ++j) {
    int i = t + j * 256, r = i >> 3, u = i & 7;
    bpre[j] = *(const us8*)&Wt[(size_t)(n0 + r) * 512 + (u << 3)];
  }
#pragma unroll
  for (int j = 0; j < MT * 2; ++j) {   // stage buf 0
    int i = t + j * 256, r = i >> 3, u = i & 7;
    *(us8*)&smem[r * 64 + ((u ^ (r & 7)) << 3)] = apre[j];
  }
#pragma unroll
  for (int j = 0; j < 4; ++j) {
    int i = t + j * 256, r = i >> 3, u = i & 7;
    *(us8*)&smem[MT * 8192 + r * 64 + ((u ^ (r & 7)) << 3)] = bpre[j];
  }

  for (int k0 = 0; k0 < 512; k0 += 64) {
    const int cur = (k0 >> 6) & 1;
    const unsigned short* AsC = &smem[cur * (MT * 4096)];
    const unsigned short* BsC = &smem[MT * 8192 + cur * 8192];
    __syncthreads();
    const bool nxt = k0 + 64 < 512;
    if (nxt) {
#pragma unroll
      for (int j = 0; j < MT * 2; ++j) {
        int i = t + j * 256, r = i >> 3, u = i & 7;
        apre[j] = *(const us8*)&A[(size_t)(m0 + r) * 512 + k0 + 64 + (u << 3)];
      }
#pragma unroll
      for (int j = 0; j < 4; ++j) {
        int i = t + j * 256, r = i >> 3, u = i & 7;
        bpre[j] = *(const us8*)&Wt[(size_t)(n0 + r) * 512 + k0 + 64 + (u << 3)];
      }
    }

#pragma unroll
    for (int kc = 0; kc < 2; ++kc) {
      bf16x8 aA[MT], bB[8];
      int u = kc * 4 + quad;
#pragma unroll
      for (int mt = 0; mt < MT; ++mt) {
        int row = w * (MT * 16) + mt * 16 + c;
        aA[mt] = *(const bf16x8*)&AsC[row * 64 + ((u ^ (c & 7)) << 3)];
      }
#pragma unroll
      for (int nt = 0; nt < 8; ++nt) {
        int row = nt * 16 + c;
        bB[nt] = *(const bf16x8*)&BsC[row * 64 + ((u ^ (c & 7)) << 3)];
      }
#pragma unroll
      for (int mt = 0; mt < MT; ++mt)
#pragma unroll
        for (int nt = 0; nt < 8; ++nt)
          acc[mt][nt] = __builtin_amdgcn_mfma_f32_16x16x32_bf16(
              aA[mt], bB[nt], acc[mt][nt], 0, 0, 0);
    }

    if (nxt) {
      unsigned short* AsN = &smem[(cur ^ 1) * (MT * 4096)];
      unsigned short* BsN = &smem[MT * 8192 + (cur ^ 1) * 8192];
#pragma unroll
      for (int j = 0; j < MT * 2; ++j) {
        int i = t + j * 256, r = i >> 3, u = i & 7;
        *(us8*)&AsN[r * 64 + ((u ^ (r & 7)) << 3)] = apre[j];
      }
#pragma unroll
      for (int j = 0; j < 4; ++j) {
        int i = t + j * 256, r = i >> 3, u = i & 7;
        *(us8*)&BsN[r * 64 + ((u ^ (r & 7)) << 3)] = bpre[j];
      }
    }
  }

  if constexpr (HEADS) {
    if (z == 2) {
      // ---- V^T epilogue via LDS transpose (pitch 152 shorts) ----
      __syncthreads();
#pragma unroll
      for (int mt = 0; mt < MT; ++mt) {
        int mb = w * (MT * 16) + mt * 16 + (quad << 2);   // mb&3 == 0
        int ml = (mb & 64) | (((mb >> 5) & 1) << 5) | (((mb >> 2) & 3) << 3) |
                 (((mb >> 4) & 1) << 2);                  // pos-permuted coord
#pragma unroll
        for (int nt = 0; nt < 8; ++nt) {
          int nl = nt * 16 + c;
          us4 pk;
#pragma unroll
          for (int r = 0; r < 4; ++r)
            pk[r] = __builtin_bit_cast(unsigned short, (_Float16)acc[mt][nt][r]);
          *(us4*)&smem[nl * 152 + ml] = pk;
        }
      }
      __syncthreads();
      const int bb = m0 >> 12, sb = m0 & 4095;
#pragma unroll
      for (int j = 0; j < MT * 4; ++j) {
        int i = t + j * 256;
        int nl = i >> 4, mc = (i & 15) << 3;
        us8 vv = *(const us8*)&smem[nl * 152 + mc];
        int n = n0 + nl, hh = n >> 6, dk = n & 63;
        *(us8*)&vtg[((size_t)(bb * Hn + hh) * DKn + dk) * Sn + sb + mc] = vv;
      }
    } else {
#pragma unroll
      for (int mt = 0; mt < MT; ++mt)
#pragma unroll
        for (int nt = 0; nt < 8; ++nt)
#pragma unroll
          for (int r = 0; r < 4; ++r) {
            int m = m0 + w * (MT * 16) + mt * 16 + (quad << 2) + r;
            int n = n0 + nt * 16 + c;
            int b = m >> 12, s = m & 4095, hh = n >> 6, dk = n & 63;
            oh[(size_t)z * (Bn * Hn * Sn * DKn) +
               ((size_t)(b * Hn + hh) * Sn + s) * DKn + dk] =
                f2bf(acc[mt][nt][r] * scale);
          }
    }
  } else {
#pragma unroll
    for (int mt = 0; mt < MT; ++mt)
#pragma unroll
      for (int nt = 0; nt < 8; ++nt)
#pragma unroll
        for (int r = 0; r < 4; ++r) {
          int m = m0 + w * (MT * 16) + mt * 16 + (quad << 2) + r;
          int n = n0 + nt * 16 + c;
          olin[(size_t)m * 512 + n] = acc[mt][nt][r];
        }
  }
}

// ------------------------------------------------------------- flash attn
// 512 thr = 2 kv-groups x 4 waves x 32 q. Group g does kv tiles (2i+g)*64
// with its own double-buffered LDS; partial (O, l) summed across groups at
// the end (static-max softmax => plain sums). PV uses f16 16x16x32 MFMA.
__global__ __launch_bounds__(512, 4) void flash_k(
    const unsigned short* __restrict__ Qh, const unsigned short* __restrict__ Kh,
    const unsigned short* __restrict__ VtG, const unsigned int* __restrict__ pmt,
    unsigned short* __restrict__ attn) {
  __shared__ unsigned short Ks[2][2][64 * 64];   // [group][parity][kv][d]
  __shared__ unsigned short Vts[2][2][64 * 64];  // [group][parity][dk][pos]
  __shared__ unsigned int Mw[2][2][256];

  const int q0 = blockIdx.x * 128, h = blockIdx.y, b = blockIdx.z;
  const int t = threadIdx.x;
  const int g = t >> 8, tg = t & 255;
  const int w = (t >> 6) & 3, l = t & 63;
  const int quad = l >> 4, c = l & 15;
  const size_t hb = (size_t)(b * Hn + h) * Sn * DKn;
  const unsigned short* Qg = Qh + hb;
  const unsigned short* Kg = Kh + hb;
  const unsigned short* Vg = VtG + hb;     // [dk][s] f16 (pos-permuted /64)

  bf16x8 bQ[2][2];
#pragma unroll
  for (int qf = 0; qf < 2; ++qf) {
    int qrow = q0 + w * 32 + qf * 16 + c;
#pragma unroll
    for (int kc = 0; kc < 2; ++kc)
      bQ[qf][kc] = *(const bf16x8*)&Qg[(size_t)qrow * 64 + kc * 32 + quad * 8];
  }

  f32x4 oacc[2][4] = {};
  float lsum[2] = {};
  const int sr = tg >> 3, su = tg & 7;
  const int off0 = sr * 64 + ((su ^ (sr & 7)) << 3);
  const int off1 = (sr + 32) * 64 + ((su ^ (sr & 7)) << 3);
  const f16x2 one2 = {(_Float16)1.0f, (_Float16)1.0f};

  us8 kpre[2], vpre[2];
  unsigned mpre;
  {
    const int kvF = g * 64;
    kpre[0] = *(const us8*)&Kg[(size_t)(kvF + sr) * 64 + (su << 3)];
    kpre[1] = *(const us8*)&Kg[(size_t)(kvF + sr + 32) * 64 + (su << 3)];
    vpre[0] = *(const us8*)&Vg[(size_t)sr * Sn + kvF + (su << 3)];
    vpre[1] = *(const us8*)&Vg[(size_t)(sr + 32) * Sn + kvF + (su << 3)];
    mpre = pmt[((size_t)b * 128 + (kvF >> 5) + (tg >> 7)) * 4096 + q0 + (tg & 127)];
    *(us8*)&Ks[g][0][off0] = kpre[0];
    *(us8*)&Ks[g][0][off1] = kpre[1];
    *(us8*)&Vts[g][0][off0] = vpre[0];
    *(us8*)&Vts[g][0][off1] = vpre[1];
    Mw[g][0][tg] = mpre;
  }

  for (int it = 0; it < 32; ++it) {
    const int cur = it & 1;
    __syncthreads();
    const bool nxt = it + 1 < 32;
    if (nxt) {
      const int kvN = (2 * (it + 1) + g) * 64;
      kpre[0] = *(const us8*)&Kg[(size_t)(kvN + sr) * 64 + (su << 3)];
      kpre[1] = *(const us8*)&Kg[(size_t)(kvN + sr + 32) * 64 + (su << 3)];
      vpre[0] = *(const us8*)&Vg[(size_t)sr * Sn + kvN + (su << 3)];
      vpre[1] = *(const us8*)&Vg[(size_t)(sr + 32) * Sn + kvN + (su << 3)];
      mpre = pmt[((size_t)b * 128 + (kvN >> 5) + (tg >> 7)) * 4096 + q0 + (tg & 127)];
    }

    // ---- S^T = K . Q^T
    f32x4 sacc[2][4] = {};
#pragma unroll
    for (int kc = 0; kc < 2; ++kc) {
      int u = kc * 4 + quad;
#pragma unroll
      for (int kvt = 0; kvt < 4; ++kvt) {
        int row = kvt * 16 + c;
        bf16x8 aK = *(const bf16x8*)&Ks[g][cur][row * 64 + ((u ^ (c & 7)) << 3)];
#pragma unroll
        for (int qf = 0; qf < 2; ++qf)
          sacc[qf][kvt] = __builtin_amdgcn_mfma_f32_16x16x32_bf16(
              aK, bQ[qf][kc], sacc[qf][kvt], 0, 0, 0);
      }
    }

    // ---- masked exp2 -> packed f16 P (registers), lsum via dot2
    f16x8 ph[2][2];   // [qf][half-of-64kv]
#pragma unroll
    for (int qf = 0; qf < 2; ++qf) {
      int qloc = w * 32 + qf * 16 + c;
      unsigned mv0 = Mw[g][cur][qloc], mv1 = Mw[g][cur][128 + qloc];
#pragma unroll
      for (int half = 0; half < 2; ++half) {
        unsigned word = half ? mv1 : mv0;
        uint4 ww;
#pragma unroll
        for (int kvh = 0; kvh < 2; ++kvh) {
          unsigned bits = (word >> ((kvh << 4) + (quad << 2))) & 15u;
          const f32x4 s4 = sacc[qf][half * 2 + kvh];
          float p0 = (bits & 1u) ? __builtin_amdgcn_exp2f(s4[0]) : 0.f;
          float p1 = (bits & 2u) ? __builtin_amdgcn_exp2f(s4[1]) : 0.f;
          float p2 = (bits & 4u) ? __builtin_amdgcn_exp2f(s4[2]) : 0.f;
          float p3 = (bits & 8u) ? __builtin_amdgcn_exp2f(s4[3]) : 0.f;
          f16x2 a = __builtin_bit_cast(f16x2, __builtin_amdgcn_cvt_pkrtz(p0, p1));
          f16x2 bpk = __builtin_bit_cast(f16x2, __builtin_amdgcn_cvt_pkrtz(p2, p3));
          lsum[qf] = __builtin_amdgcn_fdot2(a, one2, lsum[qf], false);
          lsum[qf] = __builtin_amdgcn_fdot2(bpk, one2, lsum[qf], false);
          (&ww.x)[kvh * 2] = __builtin_bit_cast(unsigned, a);
          (&ww.x)[kvh * 2 + 1] = __builtin_bit_cast(unsigned, bpk);
        }
        ph[qf][half] = __builtin_bit_cast(f16x8, ww);
      }
    }

    // ---- O += P.V  (f16 K=32; pos-permuted V^T gives the B-frag directly)
#pragma unroll
    for (int half = 0; half < 2; ++half) {
      int u2 = half * 4 + quad;
#pragma unroll
      for (int dkt = 0; dkt < 4; ++dkt) {
        int dk = dkt * 16 + c;
        f16x8 bV = __builtin_bit_cast(
            f16x8, *(const us8*)&Vts[g][cur][dk * 64 + ((u2 ^ (c & 7)) << 3)]);
#pragma unroll
        for (int qf = 0; qf < 2; ++qf)
          oacc[qf][dkt] = __builtin_amdgcn_mfma_f32_16x16x32_f16(
              ph[qf][half], bV, oacc[qf][dkt], 0, 0, 0);
      }
    }

    if (nxt) {
      const int nb = cur ^ 1;
      *(us8*)&Ks[g][nb][off0] = kpre[0];
      *(us8*)&Ks[g][nb][off1] = kpre[1];
      *(us8*)&Vts[g][nb][off0] = vpre[0];
      *(us8*)&Vts[g][nb][off1] = vpre[1];
      Mw[g][nb][tg] = mpre;
    }
  }

  // ---- combine groups (plain sums), normalize, store (group 0)
  __syncthreads();
  float* fsum = (float*)&Ks[0][0][0];          // [qf][dkt][w][l] f32x4 = 32 KB
  float* flsum = (float*)&Vts[0][0][0];        // [qf][w][l] f32 = 2 KB
  if (g == 1) {
#pragma unroll
    for (int qf = 0; qf < 2; ++qf) {
#pragma unroll
      for (int dkt = 0; dkt < 4; ++dkt)
        *(f32x4*)&fsum[(((qf * 4 + dkt) * 4 + w) * 64 + l) * 4] = oacc[qf][dkt];
      flsum[(qf * 4 + w) * 64 + l] = lsum[qf];
    }
  }
  __syncthreads();
  if (g == 0) {
#pragma unroll
    for (int qf = 0; qf < 2; ++qf) {
      lsum[qf] += flsum[(qf * 4 + w) * 64 + l];
#pragma unroll
      for (int dkt = 0; dkt < 4; ++dkt) {
        f32x4 o1 = *(const f32x4*)&fsum[(((qf * 4 + dkt) * 4 + w) * 64 + l) * 4];
#pragma unroll
        for (int r = 0; r < 4; ++r) oacc[qf][dkt][r] += o1[r];
      }
    }
#pragma unroll
    for (int qf = 0; qf < 2; ++qf) {
      float s = lsum[qf];
      s += __shfl_xor(s, 16, 64);
      s += __shfl_xor(s, 32, 64);
      float inv = 1.0f / s;
#pragma unroll
      for (int r = 0; r < 4; ++r) {
        float invr = __shfl(inv, (quad << 2) + r, 64);
        unsigned short* dst =
            &attn[((size_t)(b * Sn + q0 + w * 32 + qf * 16 + (quad << 2) + r)) * Dn +
                  h * 64 + c];
#pragma unroll
        for (int dkt = 0; dkt < 4; ++dkt)
          dst[dkt * 16] = f2bf(oacc[qf][dkt][r] * invr);
      }
    }
  }
}

// ------------------------------------------------------------------ launch
extern "C" void kernel_launch(void* const* d_in, const int* in_sizes, int n_in,
                              void* d_out, int out_size, void* d_ws,
                              size_t ws_size, hipStream_t stream) {
  const float* q = (const float*)d_in[0];
  const float* k = (const float*)d_in[1];
  const float* v = (const float*)d_in[2];
  const int* mask = (const int*)d_in[3];
  const float* wq = (const float*)d_in[4];
  const float* wk = (const float*)d_in[5];
  const float* wv = (const float*)d_in[6];
  const float* wo = (const float*)d_in[7];
  float* out = (float*)d_out;

  char* ws = (char*)d_ws;
  const size_t headN = (size_t)Bn * Hn * Sn * DKn;        // 4,194,304 elems
  const size_t tensB = headN * 2;                          // 8 MB
  unsigned short* qbkb = (unsigned short*)ws;
  unsigned short* attn = (unsigned short*)ws;              // reuse post-proj
  size_t off = 3 * tensB;
  unsigned short* qkv = (unsigned short*)(ws + off);       // Q,K heads + V^T
  off += 3 * tensB;
  unsigned short* wt = (unsigned short*)(ws + off);        // 2 MB
  off += 4ull * 512 * 512 * 2;
  unsigned int* pm = (unsigned int*)(ws + off);            // 4 MB transposed

  pack_mask_k<<<(Bn * Sn * Sn) / 256, 256, 0, stream>>>(mask, pm);
  cvt_k<<<dim3(4096, 3), 256, 0, stream>>>(q, k, v, qbkb);
  wt_k<<<dim3(8, 8, 4), 256, 0, stream>>>(wq, wk, wv, wo, wt);
  gemm_k<2, true><<<dim3(64, 4, 3), 256, 0, stream>>>(
      qbkb, headN, wt, qkv, qkv + 2 * headN, nullptr);
  flash_k<<<dim3(32, 8, 2), 512, 0, stream>>>(qkv, qkv + headN,
                                              qkv + 2 * headN, pm, attn);
  gemm_k<1, false><<<dim3(128, 4, 1), 256, 0, stream>>>(
      attn, 0, wt + 3ull * 512 * 512, nullptr, nullptr, out);
}

// Round 8
// 366.368 us; speedup vs baseline: 1.4934x; 1.0595x over previous
//
#include <hip/hip_runtime.h>
#include <hip/hip_bf16.h>

#define Bn 2
#define Sn 4096
#define Dn 512
#define Hn 8
#define DKn 64

typedef __attribute__((ext_vector_type(8))) short bf16x8;
typedef __attribute__((ext_vector_type(4))) float f32x4;
typedef __attribute__((ext_vector_type(4))) _Float16 f16x4;
typedef __attribute__((ext_vector_type(8))) _Float16 f16x8;
typedef __attribute__((ext_vector_type(2))) _Float16 f16x2;
typedef __attribute__((ext_vector_type(8))) unsigned short us8;
typedef __attribute__((ext_vector_type(4))) unsigned short us4;

__device__ __forceinline__ unsigned short f2bf(float f) {
  unsigned u = __builtin_bit_cast(unsigned, f);
  u += 0x7fffu + ((u >> 16) & 1u);   // RNE; inputs finite
  return (unsigned short)(u >> 16);
}

// -------------------------------------------------------------------- prep
// blockIdx.x < 256 : weights -> bf16 W^T tiles.
// blockIdx.x >= 256: mask 32:1 bit-pack, transposed pm[b][kvw][q], grid-stride.
__global__ __launch_bounds__(256) void prep_k(
    const int* __restrict__ mask, unsigned int* __restrict__ pm,
    const float* __restrict__ wq, const float* __restrict__ wk,
    const float* __restrict__ wv, const float* __restrict__ wo,
    unsigned short* __restrict__ wt) {
  const int t = threadIdx.x;
  if (blockIdx.x < 256) {
    __shared__ unsigned short ls[64][68];
    int bid = blockIdx.x;
    int z = bid >> 6, x = bid & 7, y = (bid >> 3) & 7;
    const float* W = z == 0 ? wq : z == 1 ? wk : z == 2 ? wv : wo;
    int k0 = x * 64, n0 = y * 64;
    for (int j = 0; j < 4; ++j) {
      int i = t + j * 256;
      int r = i >> 4, c4 = (i & 15) << 2;
      float4 f = *(const float4*)&W[(size_t)(k0 + r) * 512 + n0 + c4];
      ls[c4 + 0][r] = f2bf(f.x);
      ls[c4 + 1][r] = f2bf(f.y);
      ls[c4 + 2][r] = f2bf(f.z);
      ls[c4 + 3][r] = f2bf(f.w);
    }
    __syncthreads();
    unsigned short* out = wt + (size_t)z * 512 * 512;
    for (int j = 0; j < 4; ++j) {
      int i = t + j * 256;
      int r = i >> 4, c4 = (i & 15) << 2;
      us4 v = {ls[r][c4], ls[r][c4 + 1], ls[r][c4 + 2], ls[r][c4 + 3]};
      *(us4*)&out[(size_t)(n0 + r) * 512 + k0 + c4] = v;
    }
  } else {
    size_t idx = (size_t)(blockIdx.x - 256) * 256 + t;
    for (int it = 0; it < 8; ++it, idx += 4194304) {
      int m = mask[idx];
      unsigned long long bal = __ballot(m != 0);
      if ((t & 63) == 0) {
        int q = (int)((idx >> 12) & 4095);
        int b = (int)(idx >> 24);
        int kvw = (int)((idx >> 5) & 127);
        pm[((size_t)b * 128 + kvw) * 4096 + q] = (unsigned)bal;
        pm[((size_t)b * 128 + kvw + 1) * 4096 + q] = (unsigned)(bal >> 32);
      }
    }
  }
}

// ------------------------------------------------------------------- GEMM
// C[8192,512] = A @ W[512,512]. BM=MT*64, BN=128, BK=64, 4 waves, LDS
// double-buffered, ONE barrier per k-tile. HEADS: A is fp32 (cvt fused in
// staging); z<2 -> bf16 heads (Q scaled), z==2 -> f16 V^T pos-permuted via
// in-LDS transpose. !HEADS: A bf16, fp32 linear out.
template <int MT, bool HEADS>
__global__ __launch_bounds__(256, 2) void gemm_k(
    const float* __restrict__ aq, const float* __restrict__ ak,
    const float* __restrict__ av, const unsigned short* __restrict__ abf,
    const unsigned short* __restrict__ wt, unsigned short* __restrict__ oh,
    unsigned short* __restrict__ vtg, float* __restrict__ olin) {
  __shared__ unsigned short smem[MT * 8192 + 16384];  // As[2] | Bs[2]
  const int z = blockIdx.z;
  const float* A32 = HEADS ? (z == 0 ? aq : z == 1 ? ak : av) : nullptr;
  const unsigned short* Wt = wt + (size_t)z * 512 * 512;
  const float scale = (HEADS && z == 0) ? 0.125f * 1.44269504088896f : 1.0f;
  const int m0 = blockIdx.x * (MT * 64), n0 = blockIdx.y * 128;
  const int t = threadIdx.x, w = t >> 6, l = t & 63;
  const int quad = l >> 4, c = l & 15;

  f32x4 acc[MT][8] = {};
  us8 apre[MT * 2], bpre[4];

  auto ldA = [&](int j, int kk) -> us8 {
    int i = t + j * 256, r = i >> 3, u = i & 7;
    if constexpr (HEADS) {
      const float* s = &A32[(size_t)(m0 + r) * 512 + kk + (u << 3)];
      float4 f0 = *(const float4*)s;
      float4 f1 = *(const float4*)(s + 4);
      us8 v;
      v[0] = f2bf(f0.x); v[1] = f2bf(f0.y); v[2] = f2bf(f0.z); v[3] = f2bf(f0.w);
      v[4] = f2bf(f1.x); v[5] = f2bf(f1.y); v[6] = f2bf(f1.z); v[7] = f2bf(f1.w);
      return v;
    } else {
      return *(const us8*)&abf[(size_t)(m0 + r) * 512 + kk + (u << 3)];
    }
  };

#pragma unroll
  for (int j = 0; j < MT * 2; ++j) apre[j] = ldA(j, 0);
#pragma unroll
  for (int j = 0; j < 4; ++j) {
    int i = t + j * 256, r = i >> 3, u = i & 7;
    bpre[j] = *(const us8*)&Wt[(size_t)(n0 + r) * 512 + (u << 3)];
  }
#pragma unroll
  for (int j = 0; j < MT * 2; ++j) {   // stage buf 0
    int i = t + j * 256, r = i >> 3, u = i & 7;
    *(us8*)&smem[r * 64 + ((u ^ (r & 7)) << 3)] = apre[j];
  }
#pragma unroll
  for (int j = 0; j < 4; ++j) {
    int i = t + j * 256, r = i >> 3, u = i & 7;
    *(us8*)&smem[MT * 8192 + r * 64 + ((u ^ (r & 7)) << 3)] = bpre[j];
  }

  for (int k0 = 0; k0 < 512; k0 += 64) {
    const int cur = (k0 >> 6) & 1;
    const unsigned short* AsC = &smem[cur * (MT * 4096)];
    const unsigned short* BsC = &smem[MT * 8192 + cur * 8192];
    __syncthreads();
    const bool nxt = k0 + 64 < 512;
    if (nxt) {
#pragma unroll
      for (int j = 0; j < MT * 2; ++j) apre[j] = ldA(j, k0 + 64);
#pragma unroll
      for (int j = 0; j < 4; ++j) {
        int i = t + j * 256, r = i >> 3, u = i & 7;
        bpre[j] = *(const us8*)&Wt[(size_t)(n0 + r) * 512 + k0 + 64 + (u << 3)];
      }
    }

#pragma unroll
    for (int kc = 0; kc < 2; ++kc) {
      bf16x8 aA[MT], bB[8];
      int u = kc * 4 + quad;
#pragma unroll
      for (int mt = 0; mt < MT; ++mt) {
        int row = w * (MT * 16) + mt * 16 + c;
        aA[mt] = *(const bf16x8*)&AsC[row * 64 + ((u ^ (c & 7)) << 3)];
      }
#pragma unroll
      for (int nt = 0; nt < 8; ++nt) {
        int row = nt * 16 + c;
        bB[nt] = *(const bf16x8*)&BsC[row * 64 + ((u ^ (c & 7)) << 3)];
      }
#pragma unroll
      for (int mt = 0; mt < MT; ++mt)
#pragma unroll
        for (int nt = 0; nt < 8; ++nt)
          acc[mt][nt] = __builtin_amdgcn_mfma_f32_16x16x32_bf16(
              aA[mt], bB[nt], acc[mt][nt], 0, 0, 0);
    }

    if (nxt) {
      unsigned short* AsN = &smem[(cur ^ 1) * (MT * 4096)];
      unsigned short* BsN = &smem[MT * 8192 + (cur ^ 1) * 8192];
#pragma unroll
      for (int j = 0; j < MT * 2; ++j) {
        int i = t + j * 256, r = i >> 3, u = i & 7;
        *(us8*)&AsN[r * 64 + ((u ^ (r & 7)) << 3)] = apre[j];
      }
#pragma unroll
      for (int j = 0; j < 4; ++j) {
        int i = t + j * 256, r = i >> 3, u = i & 7;
        *(us8*)&BsN[r * 64 + ((u ^ (r & 7)) << 3)] = bpre[j];
      }
    }
  }

  if constexpr (HEADS) {
    if (z == 2) {
      // ---- V^T epilogue via LDS transpose (pitch 152 shorts) ----
      __syncthreads();
#pragma unroll
      for (int mt = 0; mt < MT; ++mt) {
        int mb = w * (MT * 16) + mt * 16 + (quad << 2);
        int ml = (mb & 64) | (((mb >> 5) & 1) << 5) | (((mb >> 2) & 3) << 3) |
                 (((mb >> 4) & 1) << 2);                  // pos-permuted coord
#pragma unroll
        for (int nt = 0; nt < 8; ++nt) {
          int nl = nt * 16 + c;
          us4 pk;
#pragma unroll
          for (int r = 0; r < 4; ++r)
            pk[r] = __builtin_bit_cast(unsigned short, (_Float16)acc[mt][nt][r]);
          *(us4*)&smem[nl * 152 + ml] = pk;
        }
      }
      __syncthreads();
      const int bb = m0 >> 12, sb = m0 & 4095;
#pragma unroll
      for (int j = 0; j < MT * 4; ++j) {
        int i = t + j * 256;
        int nl = i >> 4, mc = (i & 15) << 3;
        us8 vv = *(const us8*)&smem[nl * 152 + mc];
        int n = n0 + nl, hh = n >> 6, dk = n & 63;
        *(us8*)&vtg[((size_t)(bb * Hn + hh) * DKn + dk) * Sn + sb + mc] = vv;
      }
    } else {
#pragma unroll
      for (int mt = 0; mt < MT; ++mt)
#pragma unroll
        for (int nt = 0; nt < 8; ++nt)
#pragma unroll
          for (int r = 0; r < 4; ++r) {
            int m = m0 + w * (MT * 16) + mt * 16 + (quad << 2) + r;
            int n = n0 + nt * 16 + c;
            int b = m >> 12, s = m & 4095, hh = n >> 6, dk = n & 63;
            oh[(size_t)z * (Bn * Hn * Sn * DKn) +
               ((size_t)(b * Hn + hh) * Sn + s) * DKn + dk] =
                f2bf(acc[mt][nt][r] * scale);
          }
    }
  } else {
#pragma unroll
    for (int mt = 0; mt < MT; ++mt)
#pragma unroll
      for (int nt = 0; nt < 8; ++nt)
#pragma unroll
        for (int r = 0; r < 4; ++r) {
          int m = m0 + w * (MT * 16) + mt * 16 + (quad << 2) + r;
          int n = n0 + nt * 16 + c;
          olin[(size_t)m * 512 + n] = acc[mt][nt][r];
        }
  }
}

// ------------------------------------------------------------- flash attn
// 512 thr = 2 kv-groups x 4 waves x 32 q. Static-max softmax; P in regs;
// row-sum l via MFMA ones-trick (lane-local, no shuffles); PV f16 K=32.
__global__ __launch_bounds__(512, 4) void flash_k(
    const unsigned short* __restrict__ Qh, const unsigned short* __restrict__ Kh,
    const unsigned short* __restrict__ VtG, const unsigned int* __restrict__ pmt,
    unsigned short* __restrict__ attn) {
  __shared__ unsigned short Ks[2][2][64 * 64];   // [group][parity][kv][d]
  __shared__ unsigned short Vts[2][2][64 * 64];  // [group][parity][dk][pos]
  __shared__ unsigned int Mw[2][2][256];

  const int q0 = blockIdx.x * 128, h = blockIdx.y, b = blockIdx.z;
  const int t = threadIdx.x;
  const int g = t >> 8, tg = t & 255;
  const int w = (t >> 6) & 3, l = t & 63;
  const int quad = l >> 4, c = l & 15;
  const size_t hb = (size_t)(b * Hn + h) * Sn * DKn;
  const unsigned short* Qg = Qh + hb;

  bf16x8 bQ[2][2];
#pragma unroll
  for (int qf = 0; qf < 2; ++qf) {
    int qrow = q0 + w * 32 + qf * 16 + c;
#pragma unroll
    for (int kc = 0; kc < 2; ++kc)
      bQ[qf][kc] = *(const bf16x8*)&Qg[(size_t)qrow * 64 + kc * 32 + quad * 8];
  }

  f32x4 oacc[2][4] = {};
  f32x4 oaccl[2] = {};                 // rowsum frag: reg r <-> q = quad*4+r
  f16x8 vone8;
#pragma unroll
  for (int i = 0; i < 8; ++i) vone8[i] = (_Float16)1.0f;

  const int sr = tg >> 3, su = tg & 7;
  const int off0 = sr * 64 + ((su ^ (sr & 7)) << 3);
  const int off1 = (sr + 32) * 64 + ((su ^ (sr & 7)) << 3);

  // stepped staging pointers (tile stride: K rows +128, V cols +128, mask +4 rows)
  const unsigned short* kp0 = Kh + hb + ((size_t)(g * 64 + sr)) * 64 + (su << 3);
  const unsigned short* kp1 = kp0 + 32 * 64;
  const unsigned short* vp0 = VtG + hb + (size_t)sr * Sn + g * 64 + (su << 3);
  const unsigned short* vp1 = VtG + hb + (size_t)(sr + 32) * Sn + g * 64 + (su << 3);
  const unsigned int* mp =
      pmt + ((size_t)b * 128 + g * 2 + (tg >> 7)) * 4096 + q0 + (tg & 127);

  us8 kpre[2], vpre[2];
  unsigned mpre;
  kpre[0] = *(const us8*)kp0;
  kpre[1] = *(const us8*)kp1;
  vpre[0] = *(const us8*)vp0;
  vpre[1] = *(const us8*)vp1;
  mpre = *mp;
  *(us8*)&Ks[g][0][off0] = kpre[0];
  *(us8*)&Ks[g][0][off1] = kpre[1];
  *(us8*)&Vts[g][0][off0] = vpre[0];
  *(us8*)&Vts[g][0][off1] = vpre[1];
  Mw[g][0][tg] = mpre;

  for (int it = 0; it < 32; ++it) {
    const int cur = it & 1;
    __syncthreads();
    const bool nxt = it + 1 < 32;
    if (nxt) {
      kp0 += 8192; kp1 += 8192; vp0 += 128; vp1 += 128; mp += 16384;
      kpre[0] = *(const us8*)kp0;
      kpre[1] = *(const us8*)kp1;
      vpre[0] = *(const us8*)vp0;
      vpre[1] = *(const us8*)vp1;
      mpre = *mp;
    }

    // ---- S^T = K . Q^T
    f32x4 sacc[2][4] = {};
#pragma unroll
    for (int kc = 0; kc < 2; ++kc) {
      int u = kc * 4 + quad;
#pragma unroll
      for (int kvt = 0; kvt < 4; ++kvt) {
        int row = kvt * 16 + c;
        bf16x8 aK = *(const bf16x8*)&Ks[g][cur][row * 64 + ((u ^ (c & 7)) << 3)];
#pragma unroll
        for (int qf = 0; qf < 2; ++qf)
          sacc[qf][kvt] = __builtin_amdgcn_mfma_f32_16x16x32_bf16(
              aK, bQ[qf][kc], sacc[qf][kvt], 0, 0, 0);
      }
    }

    // ---- masked exp2 -> packed f16 P (registers)
    f16x8 ph[2][2];   // [qf][half-of-64kv]
#pragma unroll
    for (int qf = 0; qf < 2; ++qf) {
      int qloc = w * 32 + qf * 16 + c;
      unsigned mv0 = Mw[g][cur][qloc], mv1 = Mw[g][cur][128 + qloc];
#pragma unroll
      for (int half = 0; half < 2; ++half) {
        unsigned word = half ? mv1 : mv0;
        uint4 ww;
#pragma unroll
        for (int kvh = 0; kvh < 2; ++kvh) {
          unsigned bits = (word >> ((kvh << 4) + (quad << 2))) & 15u;
          const f32x4 s4 = sacc[qf][half * 2 + kvh];
          float p0 = (bits & 1u) ? __builtin_amdgcn_exp2f(s4[0]) : 0.f;
          float p1 = (bits & 2u) ? __builtin_amdgcn_exp2f(s4[1]) : 0.f;
          float p2 = (bits & 4u) ? __builtin_amdgcn_exp2f(s4[2]) : 0.f;
          float p3 = (bits & 8u) ? __builtin_amdgcn_exp2f(s4[3]) : 0.f;
          f16x2 a = __builtin_bit_cast(f16x2, __builtin_amdgcn_cvt_pkrtz(p0, p1));
          f16x2 bpk = __builtin_bit_cast(f16x2, __builtin_amdgcn_cvt_pkrtz(p2, p3));
          (&ww.x)[kvh * 2] = __builtin_bit_cast(unsigned, a);
          (&ww.x)[kvh * 2 + 1] = __builtin_bit_cast(unsigned, bpk);
        }
        ph[qf][half] = __builtin_bit_cast(f16x8, ww);
      }
    }

    // ---- O += P.V ; l += P.1 (ones-MFMA)
#pragma unroll
    for (int half = 0; half < 2; ++half) {
      int u2 = half * 4 + quad;
#pragma unroll
      for (int dkt = 0; dkt < 4; ++dkt) {
        int dk = dkt * 16 + c;
        f16x8 bV = __builtin_bit_cast(
            f16x8, *(const us8*)&Vts[g][cur][dk * 64 + ((u2 ^ (c & 7)) << 3)]);
#pragma unroll
        for (int qf = 0; qf < 2; ++qf)
          oacc[qf][dkt] = __builtin_amdgcn_mfma_f32_16x16x32_f16(
              ph[qf][half], bV, oacc[qf][dkt], 0, 0, 0);
      }
#pragma unroll
      for (int qf = 0; qf < 2; ++qf)
        oaccl[qf] = __builtin_amdgcn_mfma_f32_16x16x32_f16(
            ph[qf][half], vone8, oaccl[qf], 0, 0, 0);
    }

    if (nxt) {
      const int nb = cur ^ 1;
      *(us8*)&Ks[g][nb][off0] = kpre[0];
      *(us8*)&Ks[g][nb][off1] = kpre[1];
      *(us8*)&Vts[g][nb][off0] = vpre[0];
      *(us8*)&Vts[g][nb][off1] = vpre[1];
      Mw[g][nb][tg] = mpre;
    }
  }

  // ---- combine groups (plain sums), normalize, store (group 0)
  __syncthreads();
  float* fsum = (float*)&Ks[0][0][0];          // [qf][dkt][w][l] f32x4 = 32 KB
  float* flsum = (float*)&Vts[0][0][0];        // [qf][w][l] f32x4 = 8 KB
  if (g == 1) {
#pragma unroll
    for (int qf = 0; qf < 2; ++qf) {
#pragma unroll
      for (int dkt = 0; dkt < 4; ++dkt)
        *(f32x4*)&fsum[(((qf * 4 + dkt) * 4 + w) * 64 + l) * 4] = oacc[qf][dkt];
      *(f32x4*)&flsum[((qf * 4 + w) * 64 + l) * 4] = oaccl[qf];
    }
  }
  __syncthreads();
  if (g == 0) {
#pragma unroll
    for (int qf = 0; qf < 2; ++qf) {
      f32x4 l1 = *(const f32x4*)&flsum[((qf * 4 + w) * 64 + l) * 4];
#pragma unroll
      for (int r = 0; r < 4; ++r) oaccl[qf][r] += l1[r];
#pragma unroll
      for (int dkt = 0; dkt < 4; ++dkt) {
        f32x4 o1 = *(const f32x4*)&fsum[(((qf * 4 + dkt) * 4 + w) * 64 + l) * 4];
#pragma unroll
        for (int r = 0; r < 4; ++r) oacc[qf][dkt][r] += o1[r];
      }
    }
#pragma unroll
    for (int qf = 0; qf < 2; ++qf)
#pragma unroll
      for (int r = 0; r < 4; ++r) {
        float invr = 1.0f / oaccl[qf][r];
        unsigned short* dst =
            &attn[((size_t)(b * Sn + q0 + w * 32 + qf * 16 + (quad << 2) + r)) * Dn +
                  h * 64 + c];
#pragma unroll
        for (int dkt = 0; dkt < 4; ++dkt)
          dst[dkt * 16] = f2bf(oacc[qf][dkt][r] * invr);
      }
  }
}

// ------------------------------------------------------------------ launch
extern "C" void kernel_launch(void* const* d_in, const int* in_sizes, int n_in,
                              void* d_out, int out_size, void* d_ws,
                              size_t ws_size, hipStream_t stream) {
  const float* q = (const float*)d_in[0];
  const float* k = (const float*)d_in[1];
  const float* v = (const float*)d_in[2];
  const int* mask = (const int*)d_in[3];
  const float* wq = (const float*)d_in[4];
  const float* wk = (const float*)d_in[5];
  const float* wv = (const float*)d_in[6];
  const float* wo = (const float*)d_in[7];
  float* out = (float*)d_out;

  char* ws = (char*)d_ws;
  const size_t headN = (size_t)Bn * Hn * Sn * DKn;        // 4,194,304 elems
  const size_t tensB = headN * 2;                          // 8 MB
  unsigned short* attn = (unsigned short*)ws;
  size_t off = 3 * tensB;
  unsigned short* qkv = (unsigned short*)(ws + off);       // Q,K heads + V^T
  off += 3 * tensB;
  unsigned short* wt = (unsigned short*)(ws + off);        // 2 MB
  off += 4ull * 512 * 512 * 2;
  unsigned int* pm = (unsigned int*)(ws + off);            // 4 MB transposed

  prep_k<<<16640, 256, 0, stream>>>(mask, pm, wq, wk, wv, wo, wt);
  gemm_k<2, true><<<dim3(64, 4, 3), 256, 0, stream>>>(
      q, k, v, nullptr, wt, qkv, qkv + 2 * headN, nullptr);
  flash_k<<<dim3(32, 8, 2), 512, 0, stream>>>(qkv, qkv + headN,
                                              qkv + 2 * headN, pm, attn);
  gemm_k<1, false><<<dim3(128, 4, 1), 256, 0, stream>>>(
      nullptr, nullptr, nullptr, attn, wt + 3ull * 512 * 512, nullptr, nullptr,
      out);
}